// Round 2
// 2849.940 us; speedup vs baseline: 1.1223x; 1.1223x over previous
//
#include <hip/hip_runtime.h>
#include <math.h>

#define BB 128
#define HH 512
#define SS 80
#define NT 27      // time steps (T-1)
#define VV 30000
#define NBLK 469   // ceil(VV/64) vocab-column blocks for MFMA vproj

typedef short bf16x8 __attribute__((ext_vector_type(8)));
typedef float f32x4  __attribute__((ext_vector_type(4)));
typedef unsigned long long u64;

// ---- workspace layout (in floats) ----
#define OFF_WE     0
#define OFF_CTX    512
#define OFF_H      (OFF_CTX + BB*HH)          // 66048
#define OFF_C      (OFF_H + BB*HH)            // 131584
#define OFF_GATES  (OFF_C + BB*HH)            // 197120
#define OFF_SLOTS  (OFF_GATES + BB*2048)      // 459264
#define OFF_GCTX   (OFF_SLOTS + 2*NT*BB)      // 466176
#define OFF_GIN    (OFF_GCTX + BB*2048)       // 728320
#define WS_FULL_FLOATS (OFF_GIN + NT*BB*2048) // 7,806,208 floats
// MFMA extension: Wout hi/lo bf16, h hi/lo bf16, per-block argmax partials
#define OFF_WHI    WS_FULL_FLOATS                    // ushort[VV*512]  -> VV*256 floats
#define OFF_WLO    (OFF_WHI + VV*256)
#define OFF_HHI    (OFF_WLO + VV*256)                // ushort[BB*512]  -> BB*256 floats
#define OFF_HLO    (OFF_HHI + BB*256)
#define OFF_PART   (OFF_HLO + BB*256)                // u64[NT][NBLK][BB]
#define WS_MFMA_FLOATS (OFF_PART + NT*NBLK*BB*2)     // ~26.47M floats = ~106 MB

__device__ __forceinline__ unsigned long long pack_max(float v, int n) {
    unsigned u = __float_as_uint(v);
    unsigned key = (u & 0x80000000u) ? ~u : (u | 0x80000000u);
    return ((unsigned long long)key << 32) | (unsigned)(~(unsigned)n);
}

__device__ __forceinline__ unsigned short bf16_rne(float x) {
    unsigned u = __float_as_uint(x);
    unsigned r = (u + 0x7fffu + ((u >> 16) & 1u)) >> 16;
    return (unsigned short)r;
}
__device__ __forceinline__ float bf16f(unsigned short h) {
    return __uint_as_float((unsigned)h << 16);
}
__device__ __forceinline__ u64 shfl_xor_u64(u64 v, int m) {
    unsigned lo = (unsigned)v, hi = (unsigned)(v >> 32);
    lo = __shfl_xor(lo, m, 64);
    hi = __shfl_xor(hi, m, 64);
    return ((u64)hi << 32) | lo;
}

// ---------------- init: h = elhs, c = 0, slots = 0 ----------------
__global__ void k_init(const float* __restrict__ elhs, float* __restrict__ h,
                       float* __restrict__ c, unsigned long long* __restrict__ slots) {
    int i = blockIdx.x * blockDim.x + threadIdx.x;
    if (i < BB * HH) { h[i] = elhs[i]; c[i] = 0.f; }
    if (i < NT * BB) slots[i] = 0ull;
}

// ---------------- we = W1e^T W2^T W3^T W4^T w_att ----------------
__global__ __launch_bounds__(256) void k_we(const float* __restrict__ W1, const float* __restrict__ W2,
                                            const float* __restrict__ W3, const float* __restrict__ W4,
                                            const float* __restrict__ watt, float* __restrict__ we_out) {
    __shared__ float v[HH], v2[HH];
    int tid = threadIdx.x;
    for (int k = tid; k < HH; k += 256) v[k] = watt[k];
    __syncthreads();
    const float* Ws[3] = {W4, W3, W2};
    for (int l = 0; l < 3; ++l) {
        const float* W = Ws[l];
        for (int k = tid; k < HH; k += 256) {
            float s = 0.f;
            for (int j = 0; j < HH; ++j) s += v[j] * W[j * HH + k];
            v2[k] = s;
        }
        __syncthreads();
        for (int k = tid; k < HH; k += 256) v[k] = v2[k];
        __syncthreads();
    }
    for (int k = tid; k < HH; k += 256) {
        float s = 0.f;
        for (int j = 0; j < HH; ++j) s += v[j] * W1[j * (2 * HH) + k];
        we_out[k] = s;
    }
}

// ---------------- attention (step-invariant) ----------------
__global__ __launch_bounds__(256) void k_attn(const float* __restrict__ eo, const float* __restrict__ we,
                                              float* __restrict__ ctx) {
    __shared__ float wsm[HH];
    __shared__ float sc[SS];
    int b = blockIdx.x, tid = threadIdx.x;
    for (int k = tid; k < HH; k += 256) wsm[k] = we[k];
    __syncthreads();
    int wid = tid >> 6, lane = tid & 63;
    const float* eob = eo + (size_t)b * SS * HH;
    for (int s = wid; s < SS; s += 4) {
        float p = 0.f;
        for (int k = lane; k < HH; k += 64) p += eob[s * HH + k] * wsm[k];
        for (int off = 32; off > 0; off >>= 1) p += __shfl_down(p, off, 64);
        if (lane == 0) sc[s] = p;
    }
    __syncthreads();
    if (wid == 0) {
        float a = (lane < SS) ? sc[lane] : -INFINITY;
        float bv = (lane + 64 < SS) ? sc[lane + 64] : -INFINITY;
        float m = fmaxf(a, bv);
        for (int off = 32; off > 0; off >>= 1) m = fmaxf(m, __shfl_down(m, off, 64));
        m = __shfl(m, 0, 64);
        float e0 = (lane < SS) ? expf(a - m) : 0.f;
        float e1 = (lane + 64 < SS) ? expf(bv - m) : 0.f;
        float ssum = e0 + e1;
        for (int off = 32; off > 0; off >>= 1) ssum += __shfl_down(ssum, off, 64);
        ssum = __shfl(ssum, 0, 64);
        float inv = 1.f / ssum;
        if (lane < SS) sc[lane] = e0 * inv;
        if (lane + 64 < SS) sc[lane + 64] = e1 * inv;
    }
    __syncthreads();
    for (int hh = tid; hh < HH; hh += 256) {
        float acc = 0.f;
        for (int s = 0; s < SS; ++s) acc += sc[s] * eob[s * HH + hh];
        ctx[b * HH + hh] = acc;
    }
}

// ---------------- G_in = X @ W_ih[:, :512]^T ----------------
__global__ __launch_bounds__(256) void k_gin(const float* __restrict__ emb, const int* __restrict__ targets,
                                             const float* __restrict__ Wih, float* __restrict__ gin) {
    const int n0 = blockIdx.x * 64, m0 = blockIdx.y * 64;
    __shared__ __align__(16) float As[32][68];
    __shared__ __align__(16) float Bs[32][68];
    int tid = threadIdx.x;
    int tx = tid & 15, ty = tid >> 4;
    float acc[4][4] = {};
    for (int kt = 0; kt < 512; kt += 32) {
        #pragma unroll
        for (int i = 0; i < 2; ++i) {
            int idx = tid + i * 256;
            int mm = idx >> 3, k4 = (idx & 7) * 4;
            int m = m0 + mm;
            int t = m >> 7, b = m & 127;
            int row = targets[b * 28 + t];
            float4 v = *(const float4*)(emb + (size_t)row * 512 + kt + k4);
            As[k4 + 0][mm] = v.x; As[k4 + 1][mm] = v.y; As[k4 + 2][mm] = v.z; As[k4 + 3][mm] = v.w;
        }
        #pragma unroll
        for (int i = 0; i < 2; ++i) {
            int idx = tid + i * 256;
            int nn = idx >> 3, k4 = (idx & 7) * 4;
            float4 v = *(const float4*)(Wih + (size_t)(n0 + nn) * 1024 + kt + k4);
            Bs[k4 + 0][nn] = v.x; Bs[k4 + 1][nn] = v.y; Bs[k4 + 2][nn] = v.z; Bs[k4 + 3][nn] = v.w;
        }
        __syncthreads();
        #pragma unroll
        for (int k = 0; k < 32; ++k) {
            float4 a = *(const float4*)&As[k][ty * 4];
            float4 b4 = *(const float4*)&Bs[k][tx * 4];
            float av[4] = {a.x, a.y, a.z, a.w}, bv[4] = {b4.x, b4.y, b4.z, b4.w};
            #pragma unroll
            for (int i = 0; i < 4; ++i)
                #pragma unroll
                for (int j = 0; j < 4; ++j) acc[i][j] += av[i] * bv[j];
        }
        __syncthreads();
    }
    #pragma unroll
    for (int i = 0; i < 4; ++i) {
        int m = m0 + ty * 4 + i;
        float4 o = {acc[i][0], acc[i][1], acc[i][2], acc[i][3]};
        *(float4*)(gin + (size_t)m * 2048 + n0 + tx * 4) = o;
    }
}

// ---------------- gctx = ctx @ W_ih[:, 512:]^T + b_ih + b_hh ----------------
__global__ __launch_bounds__(256) void k_gctx(const float* __restrict__ ctx, const float* __restrict__ Wih,
                                              const float* __restrict__ bih, const float* __restrict__ bhh,
                                              float* __restrict__ gctx) {
    const int n0 = blockIdx.x * 64, m0 = blockIdx.y * 32;
    __shared__ __align__(16) float As[32][36];
    __shared__ __align__(16) float Bs[32][68];
    int tid = threadIdx.x;
    int tx = tid & 15, ty = tid >> 4;
    float acc[2][4] = {};
    for (int kt = 0; kt < 512; kt += 32) {
        {
            int mm = tid >> 3, k4 = (tid & 7) * 4;
            float4 v = *(const float4*)(ctx + (size_t)(m0 + mm) * 512 + kt + k4);
            As[k4 + 0][mm] = v.x; As[k4 + 1][mm] = v.y; As[k4 + 2][mm] = v.z; As[k4 + 3][mm] = v.w;
        }
        #pragma unroll
        for (int i = 0; i < 2; ++i) {
            int idx = tid + i * 256;
            int nn = idx >> 3, k4 = (idx & 7) * 4;
            float4 v = *(const float4*)(Wih + (size_t)(n0 + nn) * 1024 + 512 + kt + k4);
            Bs[k4 + 0][nn] = v.x; Bs[k4 + 1][nn] = v.y; Bs[k4 + 2][nn] = v.z; Bs[k4 + 3][nn] = v.w;
        }
        __syncthreads();
        #pragma unroll
        for (int k = 0; k < 32; ++k) {
            float a0 = As[k][ty * 2], a1 = As[k][ty * 2 + 1];
            float4 b4 = *(const float4*)&Bs[k][tx * 4];
            float bv[4] = {b4.x, b4.y, b4.z, b4.w};
            #pragma unroll
            for (int j = 0; j < 4; ++j) { acc[0][j] += a0 * bv[j]; acc[1][j] += a1 * bv[j]; }
        }
        __syncthreads();
    }
    #pragma unroll
    for (int i = 0; i < 2; ++i) {
        int b = m0 + ty * 2 + i;
        int n = n0 + tx * 4;
        float4 o = {acc[i][0] + bih[n] + bhh[n], acc[i][1] + bih[n + 1] + bhh[n + 1],
                    acc[i][2] + bih[n + 2] + bhh[n + 2], acc[i][3] + bih[n + 3] + bhh[n + 3]};
        *(float4*)(gctx + (size_t)b * 2048 + n) = o;
    }
}

// ---------------- gates GEMM ----------------
template <bool FULL>
__global__ __launch_bounds__(256) void k_gates(const float* __restrict__ emb, const int* __restrict__ targets,
                                               const float* __restrict__ ctx, const float* __restrict__ h,
                                               const float* __restrict__ Wih, const float* __restrict__ Whh,
                                               const float* __restrict__ bih, const float* __restrict__ bhh,
                                               const float* __restrict__ gin, const float* __restrict__ gctx,
                                               float* __restrict__ gates, int t) {
    const int n0 = blockIdx.x * 64, m0 = blockIdx.y * 32;
    __shared__ __align__(16) float As[32][36];
    __shared__ __align__(16) float Bs[32][68];
    int tid = threadIdx.x;
    int tx = tid & 15, ty = tid >> 4;
    float acc[2][4] = {};
    const int KTOT = FULL ? 1536 : 512;
    for (int kt = 0; kt < KTOT; kt += 32) {
        {
            int mm = tid >> 3, k4 = (tid & 7) * 4;
            int b = m0 + mm, k = kt + k4;
            const float* src;
            if (FULL) {
                if (k < 512) { int row = targets[b * 28 + t]; src = emb + (size_t)row * 512 + k; }
                else if (k < 1024) src = ctx + (size_t)b * 512 + (k - 512);
                else src = h + (size_t)b * 512 + (k - 1024);
            } else {
                src = h + (size_t)b * 512 + k;
            }
            float4 v = *(const float4*)src;
            As[k4 + 0][mm] = v.x; As[k4 + 1][mm] = v.y; As[k4 + 2][mm] = v.z; As[k4 + 3][mm] = v.w;
        }
        #pragma unroll
        for (int i = 0; i < 2; ++i) {
            int idx = tid + i * 256;
            int nn = idx >> 3, k4 = (idx & 7) * 4;
            int n = n0 + nn, k = kt + k4;
            const float* src;
            if (FULL) {
                if (k < 1024) src = Wih + (size_t)n * 1024 + k;
                else src = Whh + (size_t)n * 512 + (k - 1024);
            } else {
                src = Whh + (size_t)n * 512 + k;
            }
            float4 v = *(const float4*)src;
            Bs[k4 + 0][nn] = v.x; Bs[k4 + 1][nn] = v.y; Bs[k4 + 2][nn] = v.z; Bs[k4 + 3][nn] = v.w;
        }
        __syncthreads();
        #pragma unroll
        for (int k = 0; k < 32; ++k) {
            float a0 = As[k][ty * 2], a1 = As[k][ty * 2 + 1];
            float4 b4 = *(const float4*)&Bs[k][tx * 4];
            float bv[4] = {b4.x, b4.y, b4.z, b4.w};
            #pragma unroll
            for (int j = 0; j < 4; ++j) { acc[0][j] += a0 * bv[j]; acc[1][j] += a1 * bv[j]; }
        }
        __syncthreads();
    }
    #pragma unroll
    for (int i = 0; i < 2; ++i) {
        int b = m0 + ty * 2 + i;
        int n = n0 + tx * 4;
        float base[4];
        if (FULL) {
            #pragma unroll
            for (int j = 0; j < 4; ++j) base[j] = bih[n + j] + bhh[n + j];
        } else {
            const float* g1 = gin + ((size_t)t * BB + b) * 2048 + n;
            const float* g2 = gctx + (size_t)b * 2048 + n;
            #pragma unroll
            for (int j = 0; j < 4; ++j) base[j] = g1[j] + g2[j];
        }
        float4 o = {acc[i][0] + base[0], acc[i][1] + base[1], acc[i][2] + base[2], acc[i][3] + base[3]};
        *(float4*)(gates + (size_t)b * 2048 + n) = o;
    }
}

// ---------------- LSTM pointwise (old path) ----------------
__global__ void k_lstm(const float* __restrict__ gates, float* __restrict__ h, float* __restrict__ c) {
    int idx = blockIdx.x * blockDim.x + threadIdx.x;
    int b = idx >> 9, j = idx & 511;
    const float* g = gates + (size_t)b * 2048;
    float iv = g[j], fv = g[512 + j], gv = g[1024 + j], ov = g[1536 + j];
    float si = 1.f / (1.f + expf(-iv));
    float sf = 1.f / (1.f + expf(-fv));
    float so = 1.f / (1.f + expf(-ov));
    float c2 = sf * c[idx] + si * tanhf(gv);
    c[idx] = c2;
    h[idx] = so * tanhf(c2);
}

// ---------------- LSTM pointwise + bf16 hi/lo split of h (MFMA path) ----------------
__global__ void k_lstm2(const float* __restrict__ gates, float* __restrict__ h, float* __restrict__ c,
                        unsigned short* __restrict__ hHi, unsigned short* __restrict__ hLo) {
    int idx = blockIdx.x * blockDim.x + threadIdx.x;
    int b = idx >> 9, j = idx & 511;
    const float* g = gates + (size_t)b * 2048;
    float iv = g[j], fv = g[512 + j], gv = g[1024 + j], ov = g[1536 + j];
    float si = 1.f / (1.f + expf(-iv));
    float sf = 1.f / (1.f + expf(-fv));
    float so = 1.f / (1.f + expf(-ov));
    float c2 = sf * c[idx] + si * tanhf(gv);
    c[idx] = c2;
    float hv = so * tanhf(c2);
    h[idx] = hv;
    unsigned short hh = bf16_rne(hv);
    hHi[idx] = hh;
    hLo[idx] = bf16_rne(hv - bf16f(hh));
}

// ---------------- one-time split: fp32 -> (bf16 hi, bf16 lo), 4 elems/thread ----------------
__global__ __launch_bounds__(256) void k_split(const float* __restrict__ src, unsigned short* __restrict__ hi,
                                               unsigned short* __restrict__ lo, int n4) {
    int i = blockIdx.x * 256 + threadIdx.x;
    if (i >= n4) return;
    float4 v = ((const float4*)src)[i];
    unsigned short h0 = bf16_rne(v.x), h1 = bf16_rne(v.y), h2 = bf16_rne(v.z), h3 = bf16_rne(v.w);
    ushort4 hv = {h0, h1, h2, h3};
    ushort4 lv = {bf16_rne(v.x - bf16f(h0)), bf16_rne(v.y - bf16f(h1)),
                  bf16_rne(v.z - bf16f(h2)), bf16_rne(v.w - bf16f(h3))};
    ((ushort4*)hi)[i] = hv;
    ((ushort4*)lo)[i] = lv;
}

// ---------------- vocab projection via split-bf16 MFMA (3-product fp32 emulation) ----------------
// Grid: NBLK blocks x 256 threads (4 waves). Block tile: all 128 rows x 64 vocab cols.
// Wave (wm,wn): rows wm*64..+64 (4 m-tiles), cols n0+wn*32..+32 (2 n-tiles).
// Fragments loaded straight from global: A row=lane&15, k=8*(lane>>4)+i (h row-major);
// B col=lane&15, same k (Wout row-major over K). No LDS in the K-loop.
__global__ __launch_bounds__(256, 2) void k_vproj2(
    const unsigned short* __restrict__ hHi, const unsigned short* __restrict__ hLo,
    const unsigned short* __restrict__ wHi, const unsigned short* __restrict__ wLo,
    const float* __restrict__ bout, float* __restrict__ out,
    u64* __restrict__ part, int t)
{
    const int tid = threadIdx.x;
    const int lane = tid & 63;
    const int wv = tid >> 6;
    const int wm = wv >> 1;
    const int wn = wv & 1;
    const int g = lane >> 4;
    const int q = lane & 15;
    const int n0 = blockIdx.x * 64;

    int aIdx[4];
    int bIdx[2], colv[2];
    float bo[2];
    #pragma unroll
    for (int mt = 0; mt < 4; ++mt) aIdx[mt] = (wm * 64 + mt * 16 + q) * 512 + g * 8;
    #pragma unroll
    for (int nt = 0; nt < 2; ++nt) {
        int col = n0 + wn * 32 + nt * 16 + q;
        colv[nt] = col;
        int cc = col < VV ? col : (VV - 1);   // clamped dup loses argmax ties (larger packed idx)
        bIdx[nt] = cc * 512 + g * 8;
        bo[nt] = bout[cc];
    }

    f32x4 zero = {0.f, 0.f, 0.f, 0.f};
    f32x4 acc[4][2];
    #pragma unroll
    for (int mt = 0; mt < 4; ++mt)
        #pragma unroll
        for (int nt = 0; nt < 2; ++nt) acc[mt][nt] = zero;

#define LOADK(K, AH, AL, BH, BL) do {                                    \
        _Pragma("unroll") for (int mt_ = 0; mt_ < 4; ++mt_) {            \
            AH[mt_] = *(const bf16x8*)(hHi + aIdx[mt_] + (K));           \
            AL[mt_] = *(const bf16x8*)(hLo + aIdx[mt_] + (K)); }         \
        _Pragma("unroll") for (int nt_ = 0; nt_ < 2; ++nt_) {            \
            BH[nt_] = *(const bf16x8*)(wHi + bIdx[nt_] + (K));           \
            BL[nt_] = *(const bf16x8*)(wLo + bIdx[nt_] + (K)); }         \
    } while (0)

#define MM(AH, AL, BH, BL) do {                                                                     \
        _Pragma("unroll") for (int mt_ = 0; mt_ < 4; ++mt_)                                         \
        _Pragma("unroll") for (int nt_ = 0; nt_ < 2; ++nt_) {                                       \
            acc[mt_][nt_] = __builtin_amdgcn_mfma_f32_16x16x32_bf16(AH[mt_], BH[nt_], acc[mt_][nt_], 0, 0, 0); \
            acc[mt_][nt_] = __builtin_amdgcn_mfma_f32_16x16x32_bf16(AH[mt_], BL[nt_], acc[mt_][nt_], 0, 0, 0); \
            acc[mt_][nt_] = __builtin_amdgcn_mfma_f32_16x16x32_bf16(AL[mt_], BH[nt_], acc[mt_][nt_], 0, 0, 0); \
        }                                                                                           \
    } while (0)

    bf16x8 aH0[4], aL0[4], bH0[2], bL0[2];
    bf16x8 aH1[4], aL1[4], bH1[2], bL1[2];
    LOADK(0, aH0, aL0, bH0, bL0);
    #pragma unroll
    for (int s = 0; s < 16; s += 2) {
        if (s + 1 < 16) LOADK((s + 1) * 32, aH1, aL1, bH1, bL1);
        MM(aH0, aL0, bH0, bL0);
        if (s + 2 < 16) LOADK((s + 2) * 32, aH0, aL0, bH0, bL0);
        if (s + 1 < 16) MM(aH1, aL1, bH1, bL1);
    }
#undef LOADK
#undef MM

    // epilogue: bias, store logits, per-row packed argmax partial
    __shared__ u64 red[BB][2];
    #pragma unroll
    for (int mt = 0; mt < 4; ++mt) {
        #pragma unroll
        for (int r = 0; r < 4; ++r) {
            int row = wm * 64 + mt * 16 + 4 * g + r;   // batch index 0..127 (C/D: col=lane&15, row=4*(lane>>4)+reg)
            u64 pk = 0ull;
            #pragma unroll
            for (int nt = 0; nt < 2; ++nt) {
                float v = acc[mt][nt][r] + bo[nt];
                int col = colv[nt];
                if (col < VV) out[((size_t)row * NT + t) * VV + col] = v;
                u64 p2 = pack_max(v, col);
                if (p2 > pk) pk = p2;
            }
            #pragma unroll
            for (int m_ = 1; m_ < 16; m_ <<= 1) {
                u64 o = shfl_xor_u64(pk, m_);
                if (o > pk) pk = o;
            }
            if (q == 0) red[row][wn] = pk;
        }
    }
    __syncthreads();
    if (tid < BB) {
        u64 a = red[tid][0], b2 = red[tid][1];
        part[((size_t)t * NBLK + blockIdx.x) * BB + tid] = a > b2 ? a : b2;
    }
}

// ---------------- old vproj (fallback, fp32 VALU + atomic argmax) ----------------
__global__ __launch_bounds__(256) void k_vproj(const float* __restrict__ h, const float* __restrict__ Wout,
                                               const float* __restrict__ bout, float* __restrict__ out,
                                               unsigned long long* __restrict__ slots, int t) {
    const int n0 = blockIdx.x * 64, m0 = blockIdx.y * 64;
    __shared__ __align__(16) float As[32][68];
    __shared__ __align__(16) float Bs[32][68];
    __shared__ unsigned long long red[64][17];
    int tid = threadIdx.x;
    int tx = tid & 15, ty = tid >> 4;
    float acc[4][4] = {};
    for (int kt = 0; kt < 512; kt += 32) {
        #pragma unroll
        for (int i = 0; i < 2; ++i) {
            int idx = tid + i * 256;
            int mm = idx >> 3, k4 = (idx & 7) * 4;
            float4 v = *(const float4*)(h + (size_t)(m0 + mm) * 512 + kt + k4);
            As[k4 + 0][mm] = v.x; As[k4 + 1][mm] = v.y; As[k4 + 2][mm] = v.z; As[k4 + 3][mm] = v.w;
        }
        #pragma unroll
        for (int i = 0; i < 2; ++i) {
            int idx = tid + i * 256;
            int nn = idx >> 3, k4 = (idx & 7) * 4;
            int n = n0 + nn; if (n >= VV) n = VV - 1;
            float4 v = *(const float4*)(Wout + (size_t)n * 512 + kt + k4);
            Bs[k4 + 0][nn] = v.x; Bs[k4 + 1][nn] = v.y; Bs[k4 + 2][nn] = v.z; Bs[k4 + 3][nn] = v.w;
        }
        __syncthreads();
        #pragma unroll
        for (int k = 0; k < 32; ++k) {
            float4 a = *(const float4*)&As[k][ty * 4];
            float4 b4 = *(const float4*)&Bs[k][tx * 4];
            float av[4] = {a.x, a.y, a.z, a.w}, bv[4] = {b4.x, b4.y, b4.z, b4.w};
            #pragma unroll
            for (int i = 0; i < 4; ++i)
                #pragma unroll
                for (int j = 0; j < 4; ++j) acc[i][j] += av[i] * bv[j];
        }
        __syncthreads();
    }
    #pragma unroll
    for (int i = 0; i < 4; ++i) {
        int m = m0 + ty * 4 + i;
        int n = n0 + tx * 4;
        float vals[4];
        #pragma unroll
        for (int j = 0; j < 4; ++j) vals[j] = acc[i][j] + ((n + j < VV) ? bout[n + j] : 0.f);
        size_t ob = ((size_t)m * NT + t) * VV;
        if (n + 3 < VV) {
            float4 o = {vals[0], vals[1], vals[2], vals[3]};
            *(float4*)(out + ob + n) = o;
        } else {
            for (int j = 0; j < 4; ++j) if (n + j < VV) out[ob + n + j] = vals[j];
        }
        unsigned long long p = 0ull;
        #pragma unroll
        for (int j = 0; j < 4; ++j)
            if (n + j < VV) {
                unsigned long long pk = pack_max(vals[j], n + j);
                if (pk > p) p = pk;
            }
        red[ty * 4 + i][tx] = p;
    }
    __syncthreads();
    if (tid < 64) {
        unsigned long long best = red[tid][0];
        #pragma unroll
        for (int j = 1; j < 16; ++j) { unsigned long long q = red[tid][j]; if (q > best) best = q; }
        atomicMax(&slots[t * BB + (m0 + tid)], best);
    }
}

// ---------------- decode predictions (old path) ----------------
__global__ void k_final(const unsigned long long* __restrict__ slots, float* __restrict__ out) {
    int i = blockIdx.x * blockDim.x + threadIdx.x;
    if (i >= NT * BB) return;
    int t = i / BB, b = i % BB;
    unsigned idx = ~(unsigned)(slots[i] & 0xffffffffull);
    out[(size_t)BB * NT * VV + (size_t)b * NT + t] = (float)idx;
}

// ---------------- decode predictions from per-block partials (MFMA path) ----------------
__global__ void k_final2(const u64* __restrict__ part, float* __restrict__ out) {
    int i = blockIdx.x * blockDim.x + threadIdx.x;   // t*128 + b
    if (i >= NT * BB) return;
    int t = i >> 7, b = i & 127;
    const u64* p = part + (size_t)t * NBLK * BB + b;
    u64 best = 0ull;
    for (int nb = 0; nb < NBLK; ++nb) {
        u64 v = p[(size_t)nb * BB];
        if (v > best) best = v;
    }
    unsigned idx = ~(unsigned)(best & 0xffffffffull);
    out[(size_t)BB * NT * VV + (size_t)b * NT + t] = (float)idx;
}

extern "C" void kernel_launch(void* const* d_in, const int* in_sizes, int n_in,
                              void* d_out, int out_size, void* d_ws, size_t ws_size,
                              hipStream_t stream) {
    const float* elhs    = (const float*)d_in[0];
    const float* eo      = (const float*)d_in[1];
    const int*   targets = (const int*)d_in[2];
    const float* emb     = (const float*)d_in[3];
    const float* W1      = (const float*)d_in[4];
    const float* W2      = (const float*)d_in[6];
    const float* W3      = (const float*)d_in[8];
    const float* W4      = (const float*)d_in[10];
    const float* watt    = (const float*)d_in[12];
    const float* Wih     = (const float*)d_in[13];
    const float* Whh     = (const float*)d_in[14];
    const float* bih     = (const float*)d_in[15];
    const float* bhh     = (const float*)d_in[16];
    const float* Wout    = (const float*)d_in[17];
    const float* bout    = (const float*)d_in[18];

    float* out = (float*)d_out;
    float* ws  = (float*)d_ws;
    float* we    = ws + OFF_WE;
    float* ctx   = ws + OFF_CTX;
    float* h     = ws + OFF_H;
    float* c     = ws + OFF_C;
    float* gates = ws + OFF_GATES;
    unsigned long long* slots = (unsigned long long*)(ws + OFF_SLOTS);
    float* gctx  = ws + OFF_GCTX;
    float* gin   = ws + OFF_GIN;
    unsigned short* wHi = (unsigned short*)(ws + OFF_WHI);
    unsigned short* wLo = (unsigned short*)(ws + OFF_WLO);
    unsigned short* hHi = (unsigned short*)(ws + OFF_HHI);
    unsigned short* hLo = (unsigned short*)(ws + OFF_HLO);
    u64* part = (u64*)(ws + OFF_PART);

    const bool use_gin  = ws_size >= (size_t)WS_FULL_FLOATS * sizeof(float);
    const bool use_mfma = ws_size >= (size_t)WS_MFMA_FLOATS * sizeof(float);

    k_init<<<256, 256, 0, stream>>>(elhs, h, c, slots);
    k_we<<<1, 256, 0, stream>>>(W1, W2, W3, W4, watt, we);
    k_attn<<<BB, 256, 0, stream>>>(eo, we, ctx);
    if (use_mfma)
        k_split<<<(VV * 128 + 255) / 256, 256, 0, stream>>>(Wout, wHi, wLo, VV * 128);
    if (use_gin) {
        k_gin<<<dim3(32, 54), 256, 0, stream>>>(emb, targets, Wih, gin);
        k_gctx<<<dim3(32, 4), 256, 0, stream>>>(ctx, Wih, bih, bhh, gctx);
    }
    for (int t = 0; t < NT; ++t) {
        if (use_gin)
            k_gates<false><<<dim3(32, 4), 256, 0, stream>>>(emb, targets, ctx, h, Wih, Whh, bih, bhh, gin, gctx, gates, t);
        else
            k_gates<true><<<dim3(32, 4), 256, 0, stream>>>(emb, targets, ctx, h, Wih, Whh, bih, bhh, gin, gctx, gates, t);
        if (use_mfma) {
            k_lstm2<<<128, 512, 0, stream>>>(gates, h, c, hHi, hLo);
            k_vproj2<<<NBLK, 256, 0, stream>>>(hHi, hLo, wHi, wLo, bout, out, part, t);
        } else {
            k_lstm<<<128, 512, 0, stream>>>(gates, h, c);
            k_vproj<<<dim3(469, 2), 256, 0, stream>>>(h, Wout, bout, out, slots, t);
        }
    }
    if (use_mfma)
        k_final2<<<14, 256, 0, stream>>>(part, out);
    else
        k_final<<<14, 256, 0, stream>>>(slots, out);
}

// Round 3
// 2526.103 us; speedup vs baseline: 1.2662x; 1.1282x over previous
//
#include <hip/hip_runtime.h>
#include <math.h>

#define BB 128
#define HH 512
#define SS 80
#define NT 27      // time steps (T-1)
#define VV 30000
#define NBLK 469   // ceil(VV/64) vocab-column blocks

typedef short bf16x8 __attribute__((ext_vector_type(8)));
typedef float f32x4  __attribute__((ext_vector_type(4)));
typedef unsigned long long u64;

// ---- workspace layout (in floats) ----
#define OFF_WE     0
#define OFF_CTX    512
#define OFF_H      (OFF_CTX + BB*HH)          // 66048
#define OFF_C      (OFF_H + BB*HH)            // 131584
#define OFF_GATES  (OFF_C + BB*HH)            // 197120
#define OFF_SLOTS  (OFF_GATES + BB*2048)      // 459264
#define OFF_GCTX   (OFF_SLOTS + 2*NT*BB)      // 466176
#define OFF_GIN    (OFF_GCTX + BB*2048)       // 728320
#define WS_FULL_FLOATS (OFF_GIN + NT*BB*2048) // 7,806,208 floats
// ---- per-step MFMA layout (fallback, round-2 verified) ----
#define OFF_WHI    WS_FULL_FLOATS                    // ushort[VV*512]  -> VV*256 floats
#define OFF_WLO    (OFF_WHI + VV*256)
#define OFF_HHI    (OFF_WLO + VV*256)                // ushort[BB*512]
#define OFF_HLO    (OFF_HHI + BB*256)
#define OFF_PART   (OFF_HLO + BB*256)                // u64[NT][NBLK][BB]
#define WS_MFMA_FLOATS (OFF_PART + NT*NBLK*BB*2)     // ~106 MB
// ---- batched MFMA layout (primary) ----
#define OFF_WHI_B   WS_FULL_FLOATS                   // ushort[VV*512]
#define OFF_WLO_B   (OFF_WHI_B + VV*256)
#define OFF_HALLHI  (OFF_WLO_B + VV*256)             // ushort[NT*BB*512]
#define OFF_HALLLO  (OFF_HALLHI + NT*BB*256)
#define OFF_PART_B  (OFF_HALLLO + NT*BB*256)         // u64[NT][NBLK][BB]
#define WS_BATCH_FLOATS (OFF_PART_B + NT*NBLK*BB*2)  // 28,177,408 floats = ~112.7 MB

__device__ __forceinline__ unsigned long long pack_max(float v, int n) {
    unsigned u = __float_as_uint(v);
    unsigned key = (u & 0x80000000u) ? ~u : (u | 0x80000000u);
    return ((unsigned long long)key << 32) | (unsigned)(~(unsigned)n);
}

__device__ __forceinline__ unsigned short bf16_rne(float x) {
    unsigned u = __float_as_uint(x);
    unsigned r = (u + 0x7fffu + ((u >> 16) & 1u)) >> 16;
    return (unsigned short)r;
}
__device__ __forceinline__ float bf16f(unsigned short h) {
    return __uint_as_float((unsigned)h << 16);
}
__device__ __forceinline__ u64 shfl_xor_u64(u64 v, int m) {
    unsigned lo = (unsigned)v, hi = (unsigned)(v >> 32);
    lo = __shfl_xor(lo, m, 64);
    hi = __shfl_xor(hi, m, 64);
    return ((u64)hi << 32) | lo;
}

// ---------------- init: h = elhs, c = 0, slots = 0 ----------------
__global__ void k_init(const float* __restrict__ elhs, float* __restrict__ h,
                       float* __restrict__ c, unsigned long long* __restrict__ slots) {
    int i = blockIdx.x * blockDim.x + threadIdx.x;
    if (i < BB * HH) { h[i] = elhs[i]; c[i] = 0.f; }
    if (i < NT * BB) slots[i] = 0ull;
}

// ---------------- we = W1e^T W2^T W3^T W4^T w_att ----------------
__global__ __launch_bounds__(256) void k_we(const float* __restrict__ W1, const float* __restrict__ W2,
                                            const float* __restrict__ W3, const float* __restrict__ W4,
                                            const float* __restrict__ watt, float* __restrict__ we_out) {
    __shared__ float v[HH], v2[HH];
    int tid = threadIdx.x;
    for (int k = tid; k < HH; k += 256) v[k] = watt[k];
    __syncthreads();
    const float* Ws[3] = {W4, W3, W2};
    for (int l = 0; l < 3; ++l) {
        const float* W = Ws[l];
        for (int k = tid; k < HH; k += 256) {
            float s = 0.f;
            for (int j = 0; j < HH; ++j) s += v[j] * W[j * HH + k];
            v2[k] = s;
        }
        __syncthreads();
        for (int k = tid; k < HH; k += 256) v[k] = v2[k];
        __syncthreads();
    }
    for (int k = tid; k < HH; k += 256) {
        float s = 0.f;
        for (int j = 0; j < HH; ++j) s += v[j] * W1[j * (2 * HH) + k];
        we_out[k] = s;
    }
}

// ---------------- attention (step-invariant) ----------------
__global__ __launch_bounds__(256) void k_attn(const float* __restrict__ eo, const float* __restrict__ we,
                                              float* __restrict__ ctx) {
    __shared__ float wsm[HH];
    __shared__ float sc[SS];
    int b = blockIdx.x, tid = threadIdx.x;
    for (int k = tid; k < HH; k += 256) wsm[k] = we[k];
    __syncthreads();
    int wid = tid >> 6, lane = tid & 63;
    const float* eob = eo + (size_t)b * SS * HH;
    for (int s = wid; s < SS; s += 4) {
        float p = 0.f;
        for (int k = lane; k < HH; k += 64) p += eob[s * HH + k] * wsm[k];
        for (int off = 32; off > 0; off >>= 1) p += __shfl_down(p, off, 64);
        if (lane == 0) sc[s] = p;
    }
    __syncthreads();
    if (wid == 0) {
        float a = (lane < SS) ? sc[lane] : -INFINITY;
        float bv = (lane + 64 < SS) ? sc[lane + 64] : -INFINITY;
        float m = fmaxf(a, bv);
        for (int off = 32; off > 0; off >>= 1) m = fmaxf(m, __shfl_down(m, off, 64));
        m = __shfl(m, 0, 64);
        float e0 = (lane < SS) ? expf(a - m) : 0.f;
        float e1 = (lane + 64 < SS) ? expf(bv - m) : 0.f;
        float ssum = e0 + e1;
        for (int off = 32; off > 0; off >>= 1) ssum += __shfl_down(ssum, off, 64);
        ssum = __shfl(ssum, 0, 64);
        float inv = 1.f / ssum;
        if (lane < SS) sc[lane] = e0 * inv;
        if (lane + 64 < SS) sc[lane + 64] = e1 * inv;
    }
    __syncthreads();
    for (int hh = tid; hh < HH; hh += 256) {
        float acc = 0.f;
        for (int s = 0; s < SS; ++s) acc += sc[s] * eob[s * HH + hh];
        ctx[b * HH + hh] = acc;
    }
}

// ---------------- G_in = X @ W_ih[:, :512]^T ----------------
__global__ __launch_bounds__(256) void k_gin(const float* __restrict__ emb, const int* __restrict__ targets,
                                             const float* __restrict__ Wih, float* __restrict__ gin) {
    const int n0 = blockIdx.x * 64, m0 = blockIdx.y * 64;
    __shared__ __align__(16) float As[32][68];
    __shared__ __align__(16) float Bs[32][68];
    int tid = threadIdx.x;
    int tx = tid & 15, ty = tid >> 4;
    float acc[4][4] = {};
    for (int kt = 0; kt < 512; kt += 32) {
        #pragma unroll
        for (int i = 0; i < 2; ++i) {
            int idx = tid + i * 256;
            int mm = idx >> 3, k4 = (idx & 7) * 4;
            int m = m0 + mm;
            int t = m >> 7, b = m & 127;
            int row = targets[b * 28 + t];
            float4 v = *(const float4*)(emb + (size_t)row * 512 + kt + k4);
            As[k4 + 0][mm] = v.x; As[k4 + 1][mm] = v.y; As[k4 + 2][mm] = v.z; As[k4 + 3][mm] = v.w;
        }
        #pragma unroll
        for (int i = 0; i < 2; ++i) {
            int idx = tid + i * 256;
            int nn = idx >> 3, k4 = (idx & 7) * 4;
            float4 v = *(const float4*)(Wih + (size_t)(n0 + nn) * 1024 + kt + k4);
            Bs[k4 + 0][nn] = v.x; Bs[k4 + 1][nn] = v.y; Bs[k4 + 2][nn] = v.z; Bs[k4 + 3][nn] = v.w;
        }
        __syncthreads();
        #pragma unroll
        for (int k = 0; k < 32; ++k) {
            float4 a = *(const float4*)&As[k][ty * 4];
            float4 b4 = *(const float4*)&Bs[k][tx * 4];
            float av[4] = {a.x, a.y, a.z, a.w}, bv[4] = {b4.x, b4.y, b4.z, b4.w};
            #pragma unroll
            for (int i = 0; i < 4; ++i)
                #pragma unroll
                for (int j = 0; j < 4; ++j) acc[i][j] += av[i] * bv[j];
        }
        __syncthreads();
    }
    #pragma unroll
    for (int i = 0; i < 4; ++i) {
        int m = m0 + ty * 4 + i;
        float4 o = {acc[i][0], acc[i][1], acc[i][2], acc[i][3]};
        *(float4*)(gin + (size_t)m * 2048 + n0 + tx * 4) = o;
    }
}

// ---------------- gctx = ctx @ W_ih[:, 512:]^T + b_ih + b_hh ----------------
__global__ __launch_bounds__(256) void k_gctx(const float* __restrict__ ctx, const float* __restrict__ Wih,
                                              const float* __restrict__ bih, const float* __restrict__ bhh,
                                              float* __restrict__ gctx) {
    const int n0 = blockIdx.x * 64, m0 = blockIdx.y * 32;
    __shared__ __align__(16) float As[32][36];
    __shared__ __align__(16) float Bs[32][68];
    int tid = threadIdx.x;
    int tx = tid & 15, ty = tid >> 4;
    float acc[2][4] = {};
    for (int kt = 0; kt < 512; kt += 32) {
        {
            int mm = tid >> 3, k4 = (tid & 7) * 4;
            float4 v = *(const float4*)(ctx + (size_t)(m0 + mm) * 512 + kt + k4);
            As[k4 + 0][mm] = v.x; As[k4 + 1][mm] = v.y; As[k4 + 2][mm] = v.z; As[k4 + 3][mm] = v.w;
        }
        #pragma unroll
        for (int i = 0; i < 2; ++i) {
            int idx = tid + i * 256;
            int nn = idx >> 3, k4 = (idx & 7) * 4;
            float4 v = *(const float4*)(Wih + (size_t)(n0 + nn) * 1024 + 512 + kt + k4);
            Bs[k4 + 0][nn] = v.x; Bs[k4 + 1][nn] = v.y; Bs[k4 + 2][nn] = v.z; Bs[k4 + 3][nn] = v.w;
        }
        __syncthreads();
        #pragma unroll
        for (int k = 0; k < 32; ++k) {
            float a0 = As[k][ty * 2], a1 = As[k][ty * 2 + 1];
            float4 b4 = *(const float4*)&Bs[k][tx * 4];
            float bv[4] = {b4.x, b4.y, b4.z, b4.w};
            #pragma unroll
            for (int j = 0; j < 4; ++j) { acc[0][j] += a0 * bv[j]; acc[1][j] += a1 * bv[j]; }
        }
        __syncthreads();
    }
    #pragma unroll
    for (int i = 0; i < 2; ++i) {
        int b = m0 + ty * 2 + i;
        int n = n0 + tx * 4;
        float4 o = {acc[i][0] + bih[n] + bhh[n], acc[i][1] + bih[n + 1] + bhh[n + 1],
                    acc[i][2] + bih[n + 2] + bhh[n + 2], acc[i][3] + bih[n + 3] + bhh[n + 3]};
        *(float4*)(gctx + (size_t)b * 2048 + n) = o;
    }
}

// ---------------- gates GEMM ----------------
template <bool FULL>
__global__ __launch_bounds__(256) void k_gates(const float* __restrict__ emb, const int* __restrict__ targets,
                                               const float* __restrict__ ctx, const float* __restrict__ h,
                                               const float* __restrict__ Wih, const float* __restrict__ Whh,
                                               const float* __restrict__ bih, const float* __restrict__ bhh,
                                               const float* __restrict__ gin, const float* __restrict__ gctx,
                                               float* __restrict__ gates, int t) {
    const int n0 = blockIdx.x * 64, m0 = blockIdx.y * 32;
    __shared__ __align__(16) float As[32][36];
    __shared__ __align__(16) float Bs[32][68];
    int tid = threadIdx.x;
    int tx = tid & 15, ty = tid >> 4;
    float acc[2][4] = {};
    const int KTOT = FULL ? 1536 : 512;
    for (int kt = 0; kt < KTOT; kt += 32) {
        {
            int mm = tid >> 3, k4 = (tid & 7) * 4;
            int b = m0 + mm, k = kt + k4;
            const float* src;
            if (FULL) {
                if (k < 512) { int row = targets[b * 28 + t]; src = emb + (size_t)row * 512 + k; }
                else if (k < 1024) src = ctx + (size_t)b * 512 + (k - 512);
                else src = h + (size_t)b * 512 + (k - 1024);
            } else {
                src = h + (size_t)b * 512 + k;
            }
            float4 v = *(const float4*)src;
            As[k4 + 0][mm] = v.x; As[k4 + 1][mm] = v.y; As[k4 + 2][mm] = v.z; As[k4 + 3][mm] = v.w;
        }
        #pragma unroll
        for (int i = 0; i < 2; ++i) {
            int idx = tid + i * 256;
            int nn = idx >> 3, k4 = (idx & 7) * 4;
            int n = n0 + nn, k = kt + k4;
            const float* src;
            if (FULL) {
                if (k < 1024) src = Wih + (size_t)n * 1024 + k;
                else src = Whh + (size_t)n * 512 + (k - 1024);
            } else {
                src = Whh + (size_t)n * 512 + k;
            }
            float4 v = *(const float4*)src;
            Bs[k4 + 0][nn] = v.x; Bs[k4 + 1][nn] = v.y; Bs[k4 + 2][nn] = v.z; Bs[k4 + 3][nn] = v.w;
        }
        __syncthreads();
        #pragma unroll
        for (int k = 0; k < 32; ++k) {
            float a0 = As[k][ty * 2], a1 = As[k][ty * 2 + 1];
            float4 b4 = *(const float4*)&Bs[k][tx * 4];
            float bv[4] = {b4.x, b4.y, b4.z, b4.w};
            #pragma unroll
            for (int j = 0; j < 4; ++j) { acc[0][j] += a0 * bv[j]; acc[1][j] += a1 * bv[j]; }
        }
        __syncthreads();
    }
    #pragma unroll
    for (int i = 0; i < 2; ++i) {
        int b = m0 + ty * 2 + i;
        int n = n0 + tx * 4;
        float base[4];
        if (FULL) {
            #pragma unroll
            for (int j = 0; j < 4; ++j) base[j] = bih[n + j] + bhh[n + j];
        } else {
            const float* g1 = gin + ((size_t)t * BB + b) * 2048 + n;
            const float* g2 = gctx + (size_t)b * 2048 + n;
            #pragma unroll
            for (int j = 0; j < 4; ++j) base[j] = g1[j] + g2[j];
        }
        float4 o = {acc[i][0] + base[0], acc[i][1] + base[1], acc[i][2] + base[2], acc[i][3] + base[3]};
        *(float4*)(gates + (size_t)b * 2048 + n) = o;
    }
}

// ---------------- LSTM pointwise (fp32-only path) ----------------
__global__ void k_lstm(const float* __restrict__ gates, float* __restrict__ h, float* __restrict__ c) {
    int idx = blockIdx.x * blockDim.x + threadIdx.x;
    int b = idx >> 9, j = idx & 511;
    const float* g = gates + (size_t)b * 2048;
    float iv = g[j], fv = g[512 + j], gv = g[1024 + j], ov = g[1536 + j];
    float si = 1.f / (1.f + expf(-iv));
    float sf = 1.f / (1.f + expf(-fv));
    float so = 1.f / (1.f + expf(-ov));
    float c2 = sf * c[idx] + si * tanhf(gv);
    c[idx] = c2;
    h[idx] = so * tanhf(c2);
}

// ---------------- LSTM pointwise + bf16 hi/lo split of h (MFMA paths) ----------------
// hHi/hLo point at the slab for this t (batched) or a single slab (per-step).
__global__ void k_lstm2(const float* __restrict__ gates, float* __restrict__ h, float* __restrict__ c,
                        unsigned short* __restrict__ hHi, unsigned short* __restrict__ hLo) {
    int idx = blockIdx.x * blockDim.x + threadIdx.x;
    int b = idx >> 9, j = idx & 511;
    const float* g = gates + (size_t)b * 2048;
    float iv = g[j], fv = g[512 + j], gv = g[1024 + j], ov = g[1536 + j];
    float si = 1.f / (1.f + expf(-iv));
    float sf = 1.f / (1.f + expf(-fv));
    float so = 1.f / (1.f + expf(-ov));
    float c2 = sf * c[idx] + si * tanhf(gv);
    c[idx] = c2;
    float hv = so * tanhf(c2);
    h[idx] = hv;
    unsigned short hh = bf16_rne(hv);
    hHi[idx] = hh;
    hLo[idx] = bf16_rne(hv - bf16f(hh));
}

// ---------------- one-time split: fp32 -> (bf16 hi, bf16 lo) ----------------
__global__ __launch_bounds__(256) void k_split(const float* __restrict__ src, unsigned short* __restrict__ hi,
                                               unsigned short* __restrict__ lo, int n4) {
    int i = blockIdx.x * 256 + threadIdx.x;
    if (i >= n4) return;
    float4 v = ((const float4*)src)[i];
    unsigned short h0 = bf16_rne(v.x), h1 = bf16_rne(v.y), h2 = bf16_rne(v.z), h3 = bf16_rne(v.w);
    ushort4 hv = {h0, h1, h2, h3};
    ushort4 lv = {bf16_rne(v.x - bf16f(h0)), bf16_rne(v.y - bf16f(h1)),
                  bf16_rne(v.z - bf16f(h2)), bf16_rne(v.w - bf16f(h3))};
    ((ushort4*)hi)[i] = hv;
    ((ushort4*)lo)[i] = lv;
}

// ---------------- BATCHED vocab projection: all 27 steps in one dispatch ----------------
// M = NT*128 = 3456, N = 30000, K = 512, split-bf16 3-product MFMA.
// Grid: NBLK*NT blocks, 256 threads (4 waves). nblk = bid/NT, t = bid%NT, so
// consecutive blocks share the same 128KB weight slab (L2-hot).
// Block tile: 128 rows (batch of step t) x 64 cols. Wave wv: rows wv*32..+32 (2 m-tiles),
// all 64 cols (4 n-tiles). Single-buffered fragment loads (low VGPR — the round-2
// double-buffered version spilled and ran ~90 µs/block). No LDS, no syncthreads:
// waves own disjoint rows, argmax partial reduced via 16-lane shfl_xor.
__global__ __launch_bounds__(256, 3) void k_vprojB(
    const unsigned short* __restrict__ hAllHi, const unsigned short* __restrict__ hAllLo,
    const unsigned short* __restrict__ wHi, const unsigned short* __restrict__ wLo,
    const float* __restrict__ bout, float* __restrict__ out,
    u64* __restrict__ part)
{
    const int bid = blockIdx.x;
    const int nblk = bid / NT;
    const int t = bid - nblk * NT;
    const int n0 = nblk * 64;
    const int tid = threadIdx.x;
    const int lane = tid & 63;
    const int wv = tid >> 6;
    const int g = lane >> 4;
    const int q = lane & 15;

    int aIdx[2];
    int bIdx[4], colv[4];
    float bo[4];
    #pragma unroll
    for (int mt = 0; mt < 2; ++mt)
        aIdx[mt] = ((t * BB) + wv * 32 + mt * 16 + q) * 512 + g * 8;
    #pragma unroll
    for (int nt = 0; nt < 4; ++nt) {
        int col = n0 + nt * 16 + q;
        colv[nt] = col;
        int cc = col < VV ? col : (VV - 1);   // clamped dup can't win argmax (larger idx loses tie)
        bIdx[nt] = cc * 512 + g * 8;
        bo[nt] = bout[cc];
    }

    f32x4 zero = {0.f, 0.f, 0.f, 0.f};
    f32x4 acc[2][4];
    #pragma unroll
    for (int mt = 0; mt < 2; ++mt)
        #pragma unroll
        for (int nt = 0; nt < 4; ++nt) acc[mt][nt] = zero;

    for (int s = 0; s < 16; ++s) {
        const int K = s * 32;
        bf16x8 aH[2], aL[2], bH[4], bL[4];
        #pragma unroll
        for (int mt = 0; mt < 2; ++mt) {
            aH[mt] = *(const bf16x8*)(hAllHi + aIdx[mt] + K);
            aL[mt] = *(const bf16x8*)(hAllLo + aIdx[mt] + K);
        }
        #pragma unroll
        for (int nt = 0; nt < 4; ++nt) {
            bH[nt] = *(const bf16x8*)(wHi + bIdx[nt] + K);
            bL[nt] = *(const bf16x8*)(wLo + bIdx[nt] + K);
        }
        #pragma unroll
        for (int mt = 0; mt < 2; ++mt)
            #pragma unroll
            for (int nt = 0; nt < 4; ++nt) {
                acc[mt][nt] = __builtin_amdgcn_mfma_f32_16x16x32_bf16(aH[mt], bH[nt], acc[mt][nt], 0, 0, 0);
                acc[mt][nt] = __builtin_amdgcn_mfma_f32_16x16x32_bf16(aH[mt], bL[nt], acc[mt][nt], 0, 0, 0);
                acc[mt][nt] = __builtin_amdgcn_mfma_f32_16x16x32_bf16(aL[mt], bH[nt], acc[mt][nt], 0, 0, 0);
            }
    }

    // epilogue: bias, store logits, per-row argmax partial (C/D: col=lane&15, row=4*(lane>>4)+reg)
    #pragma unroll
    for (int mt = 0; mt < 2; ++mt) {
        #pragma unroll
        for (int r = 0; r < 4; ++r) {
            int row = wv * 32 + mt * 16 + 4 * g + r;   // batch index 0..127
            u64 pk = 0ull;
            #pragma unroll
            for (int nt = 0; nt < 4; ++nt) {
                float v = acc[mt][nt][r] + bo[nt];
                int col = colv[nt];
                if (col < VV) out[((size_t)row * NT + t) * VV + col] = v;
                u64 p2 = pack_max(v, col);
                if (p2 > pk) pk = p2;
            }
            #pragma unroll
            for (int m_ = 1; m_ < 16; m_ <<= 1) {
                u64 o = shfl_xor_u64(pk, m_);
                if (o > pk) pk = o;
            }
            if (q == 0) part[((size_t)t * NBLK + nblk) * BB + row] = pk;
        }
    }
}

// ---------------- per-step MFMA vproj (fallback, round-2 verified) ----------------
__global__ __launch_bounds__(256, 2) void k_vproj2(
    const unsigned short* __restrict__ hHi, const unsigned short* __restrict__ hLo,
    const unsigned short* __restrict__ wHi, const unsigned short* __restrict__ wLo,
    const float* __restrict__ bout, float* __restrict__ out,
    u64* __restrict__ part, int t)
{
    const int tid = threadIdx.x;
    const int lane = tid & 63;
    const int wv = tid >> 6;
    const int wm = wv >> 1;
    const int wn = wv & 1;
    const int g = lane >> 4;
    const int q = lane & 15;
    const int n0 = blockIdx.x * 64;

    int aIdx[4];
    int bIdx[2], colv[2];
    float bo[2];
    #pragma unroll
    for (int mt = 0; mt < 4; ++mt) aIdx[mt] = (wm * 64 + mt * 16 + q) * 512 + g * 8;
    #pragma unroll
    for (int nt = 0; nt < 2; ++nt) {
        int col = n0 + wn * 32 + nt * 16 + q;
        colv[nt] = col;
        int cc = col < VV ? col : (VV - 1);
        bIdx[nt] = cc * 512 + g * 8;
        bo[nt] = bout[cc];
    }

    f32x4 zero = {0.f, 0.f, 0.f, 0.f};
    f32x4 acc[4][2];
    #pragma unroll
    for (int mt = 0; mt < 4; ++mt)
        #pragma unroll
        for (int nt = 0; nt < 2; ++nt) acc[mt][nt] = zero;

    for (int s = 0; s < 16; ++s) {
        const int K = s * 32;
        bf16x8 aH[4], aL[4], bH[2], bL[2];
        #pragma unroll
        for (int mt = 0; mt < 4; ++mt) {
            aH[mt] = *(const bf16x8*)(hHi + aIdx[mt] + K);
            aL[mt] = *(const bf16x8*)(hLo + aIdx[mt] + K);
        }
        #pragma unroll
        for (int nt = 0; nt < 2; ++nt) {
            bH[nt] = *(const bf16x8*)(wHi + bIdx[nt] + K);
            bL[nt] = *(const bf16x8*)(wLo + bIdx[nt] + K);
        }
        #pragma unroll
        for (int mt = 0; mt < 4; ++mt)
            #pragma unroll
            for (int nt = 0; nt < 2; ++nt) {
                acc[mt][nt] = __builtin_amdgcn_mfma_f32_16x16x32_bf16(aH[mt], bH[nt], acc[mt][nt], 0, 0, 0);
                acc[mt][nt] = __builtin_amdgcn_mfma_f32_16x16x32_bf16(aH[mt], bL[nt], acc[mt][nt], 0, 0, 0);
                acc[mt][nt] = __builtin_amdgcn_mfma_f32_16x16x32_bf16(aL[mt], bH[nt], acc[mt][nt], 0, 0, 0);
            }
    }

    __shared__ u64 red[BB][2];
    #pragma unroll
    for (int mt = 0; mt < 4; ++mt) {
        #pragma unroll
        for (int r = 0; r < 4; ++r) {
            int row = wm * 64 + mt * 16 + 4 * g + r;
            u64 pk = 0ull;
            #pragma unroll
            for (int nt = 0; nt < 2; ++nt) {
                float v = acc[mt][nt][r] + bo[nt];
                int col = colv[nt];
                if (col < VV) out[((size_t)row * NT + t) * VV + col] = v;
                u64 p2 = pack_max(v, col);
                if (p2 > pk) pk = p2;
            }
            #pragma unroll
            for (int m_ = 1; m_ < 16; m_ <<= 1) {
                u64 o = shfl_xor_u64(pk, m_);
                if (o > pk) pk = o;
            }
            if (q == 0) red[row][wn] = pk;
        }
    }
    __syncthreads();
    if (tid < BB) {
        u64 a = red[tid][0], b2 = red[tid][1];
        part[((size_t)t * NBLK + blockIdx.x) * BB + tid] = a > b2 ? a : b2;
    }
}

// ---------------- old fp32 vproj (deep fallback) ----------------
__global__ __launch_bounds__(256) void k_vproj(const float* __restrict__ h, const float* __restrict__ Wout,
                                               const float* __restrict__ bout, float* __restrict__ out,
                                               unsigned long long* __restrict__ slots, int t) {
    const int n0 = blockIdx.x * 64, m0 = blockIdx.y * 64;
    __shared__ __align__(16) float As[32][68];
    __shared__ __align__(16) float Bs[32][68];
    __shared__ unsigned long long red[64][17];
    int tid = threadIdx.x;
    int tx = tid & 15, ty = tid >> 4;
    float acc[4][4] = {};
    for (int kt = 0; kt < 512; kt += 32) {
        #pragma unroll
        for (int i = 0; i < 2; ++i) {
            int idx = tid + i * 256;
            int mm = idx >> 3, k4 = (idx & 7) * 4;
            float4 v = *(const float4*)(h + (size_t)(m0 + mm) * 512 + kt + k4);
            As[k4 + 0][mm] = v.x; As[k4 + 1][mm] = v.y; As[k4 + 2][mm] = v.z; As[k4 + 3][mm] = v.w;
        }
        #pragma unroll
        for (int i = 0; i < 2; ++i) {
            int idx = tid + i * 256;
            int nn = idx >> 3, k4 = (idx & 7) * 4;
            int n = n0 + nn; if (n >= VV) n = VV - 1;
            float4 v = *(const float4*)(Wout + (size_t)n * 512 + kt + k4);
            Bs[k4 + 0][nn] = v.x; Bs[k4 + 1][nn] = v.y; Bs[k4 + 2][nn] = v.z; Bs[k4 + 3][nn] = v.w;
        }
        __syncthreads();
        #pragma unroll
        for (int k = 0; k < 32; ++k) {
            float4 a = *(const float4*)&As[k][ty * 4];
            float4 b4 = *(const float4*)&Bs[k][tx * 4];
            float av[4] = {a.x, a.y, a.z, a.w}, bv[4] = {b4.x, b4.y, b4.z, b4.w};
            #pragma unroll
            for (int i = 0; i < 4; ++i)
                #pragma unroll
                for (int j = 0; j < 4; ++j) acc[i][j] += av[i] * bv[j];
        }
        __syncthreads();
    }
    #pragma unroll
    for (int i = 0; i < 4; ++i) {
        int m = m0 + ty * 4 + i;
        int n = n0 + tx * 4;
        float vals[4];
        #pragma unroll
        for (int j = 0; j < 4; ++j) vals[j] = acc[i][j] + ((n + j < VV) ? bout[n + j] : 0.f);
        size_t ob = ((size_t)m * NT + t) * VV;
        if (n + 3 < VV) {
            float4 o = {vals[0], vals[1], vals[2], vals[3]};
            *(float4*)(out + ob + n) = o;
        } else {
            for (int j = 0; j < 4; ++j) if (n + j < VV) out[ob + n + j] = vals[j];
        }
        unsigned long long p = 0ull;
        #pragma unroll
        for (int j = 0; j < 4; ++j)
            if (n + j < VV) {
                unsigned long long pk = pack_max(vals[j], n + j);
                if (pk > p) p = pk;
            }
        red[ty * 4 + i][tx] = p;
    }
    __syncthreads();
    if (tid < 64) {
        unsigned long long best = red[tid][0];
        #pragma unroll
        for (int j = 1; j < 16; ++j) { unsigned long long q = red[tid][j]; if (q > best) best = q; }
        atomicMax(&slots[t * BB + (m0 + tid)], best);
    }
}

// ---------------- decode predictions (fp32 path) ----------------
__global__ void k_final(const unsigned long long* __restrict__ slots, float* __restrict__ out) {
    int i = blockIdx.x * blockDim.x + threadIdx.x;
    if (i >= NT * BB) return;
    int t = i / BB, b = i % BB;
    unsigned idx = ~(unsigned)(slots[i] & 0xffffffffull);
    out[(size_t)BB * NT * VV + (size_t)b * NT + t] = (float)idx;
}

// ---------------- decode predictions from per-block partials (MFMA paths) ----------------
__global__ void k_final2(const u64* __restrict__ part, float* __restrict__ out) {
    int i = blockIdx.x * blockDim.x + threadIdx.x;   // t*128 + b
    if (i >= NT * BB) return;
    int t = i >> 7, b = i & 127;
    const u64* p = part + (size_t)t * NBLK * BB + b;
    u64 best = 0ull;
    for (int nb = 0; nb < NBLK; ++nb) {
        u64 v = p[(size_t)nb * BB];
        if (v > best) best = v;
    }
    unsigned idx = ~(unsigned)(best & 0xffffffffull);
    out[(size_t)BB * NT * VV + (size_t)b * NT + t] = (float)idx;
}

extern "C" void kernel_launch(void* const* d_in, const int* in_sizes, int n_in,
                              void* d_out, int out_size, void* d_ws, size_t ws_size,
                              hipStream_t stream) {
    const float* elhs    = (const float*)d_in[0];
    const float* eo      = (const float*)d_in[1];
    const int*   targets = (const int*)d_in[2];
    const float* emb     = (const float*)d_in[3];
    const float* W1      = (const float*)d_in[4];
    const float* W2      = (const float*)d_in[6];
    const float* W3      = (const float*)d_in[8];
    const float* W4      = (const float*)d_in[10];
    const float* watt    = (const float*)d_in[12];
    const float* Wih     = (const float*)d_in[13];
    const float* Whh     = (const float*)d_in[14];
    const float* bih     = (const float*)d_in[15];
    const float* bhh     = (const float*)d_in[16];
    const float* Wout    = (const float*)d_in[17];
    const float* bout    = (const float*)d_in[18];

    float* out = (float*)d_out;
    float* ws  = (float*)d_ws;
    float* we    = ws + OFF_WE;
    float* ctx   = ws + OFF_CTX;
    float* h     = ws + OFF_H;
    float* c     = ws + OFF_C;
    float* gates = ws + OFF_GATES;
    unsigned long long* slots = (unsigned long long*)(ws + OFF_SLOTS);
    float* gctx  = ws + OFF_GCTX;
    float* gin   = ws + OFF_GIN;

    const bool use_gin   = ws_size >= (size_t)WS_FULL_FLOATS * sizeof(float);
    const bool use_batch = ws_size >= (size_t)WS_BATCH_FLOATS * sizeof(float);
    const bool use_mfma  = !use_batch && ws_size >= (size_t)WS_MFMA_FLOATS * sizeof(float);

    k_init<<<256, 256, 0, stream>>>(elhs, h, c, slots);
    k_we<<<1, 256, 0, stream>>>(W1, W2, W3, W4, watt, we);
    k_attn<<<BB, 256, 0, stream>>>(eo, we, ctx);
    if (use_gin) {
        k_gin<<<dim3(32, 54), 256, 0, stream>>>(emb, targets, Wih, gin);
        k_gctx<<<dim3(32, 4), 256, 0, stream>>>(ctx, Wih, bih, bhh, gctx);
    }

    if (use_batch) {
        unsigned short* wHi    = (unsigned short*)(ws + OFF_WHI_B);
        unsigned short* wLo    = (unsigned short*)(ws + OFF_WLO_B);
        unsigned short* hAllHi = (unsigned short*)(ws + OFF_HALLHI);
        unsigned short* hAllLo = (unsigned short*)(ws + OFF_HALLLO);
        u64* part = (u64*)(ws + OFF_PART_B);
        k_split<<<(VV * 128 + 255) / 256, 256, 0, stream>>>(Wout, wHi, wLo, VV * 128);
        for (int t = 0; t < NT; ++t) {
            if (use_gin)
                k_gates<false><<<dim3(32, 4), 256, 0, stream>>>(emb, targets, ctx, h, Wih, Whh, bih, bhh, gin, gctx, gates, t);
            else
                k_gates<true><<<dim3(32, 4), 256, 0, stream>>>(emb, targets, ctx, h, Wih, Whh, bih, bhh, gin, gctx, gates, t);
            k_lstm2<<<128, 512, 0, stream>>>(gates, h, c,
                                             hAllHi + (size_t)t * BB * 512,
                                             hAllLo + (size_t)t * BB * 512);
        }
        k_vprojB<<<NBLK * NT, 256, 0, stream>>>(hAllHi, hAllLo, wHi, wLo, bout, out, part);
        k_final2<<<14, 256, 0, stream>>>(part, out);
    } else if (use_mfma) {
        unsigned short* wHi = (unsigned short*)(ws + OFF_WHI);
        unsigned short* wLo = (unsigned short*)(ws + OFF_WLO);
        unsigned short* hHi = (unsigned short*)(ws + OFF_HHI);
        unsigned short* hLo = (unsigned short*)(ws + OFF_HLO);
        u64* part = (u64*)(ws + OFF_PART);
        k_split<<<(VV * 128 + 255) / 256, 256, 0, stream>>>(Wout, wHi, wLo, VV * 128);
        for (int t = 0; t < NT; ++t) {
            if (use_gin)
                k_gates<false><<<dim3(32, 4), 256, 0, stream>>>(emb, targets, ctx, h, Wih, Whh, bih, bhh, gin, gctx, gates, t);
            else
                k_gates<true><<<dim3(32, 4), 256, 0, stream>>>(emb, targets, ctx, h, Wih, Whh, bih, bhh, gin, gctx, gates, t);
            k_lstm2<<<128, 512, 0, stream>>>(gates, h, c, hHi, hLo);
            k_vproj2<<<NBLK, 256, 0, stream>>>(hHi, hLo, wHi, wLo, bout, out, part, t);
        }
        k_final2<<<14, 256, 0, stream>>>(part, out);
    } else {
        for (int t = 0; t < NT; ++t) {
            if (use_gin)
                k_gates<false><<<dim3(32, 4), 256, 0, stream>>>(emb, targets, ctx, h, Wih, Whh, bih, bhh, gin, gctx, gates, t);
            else
                k_gates<true><<<dim3(32, 4), 256, 0, stream>>>(emb, targets, ctx, h, Wih, Whh, bih, bhh, gin, gctx, gates, t);
            k_lstm<<<128, 512, 0, stream>>>(gates, h, c);
            k_vproj<<<dim3(469, 2), 256, 0, stream>>>(h, Wout, bout, out, slots, t);
        }
        k_final<<<14, 256, 0, stream>>>(slots, out);
    }
}

// Round 4
// 2464.632 us; speedup vs baseline: 1.2978x; 1.0249x over previous
//
#include <hip/hip_runtime.h>
#include <math.h>

#define BB 128
#define HH 512
#define SS 80
#define NT 27      // time steps (T-1)
#define VV 30000
#define NBLK 469   // ceil(VV/64) vocab-column blocks

typedef short bf16x8 __attribute__((ext_vector_type(8)));
typedef float f32x4  __attribute__((ext_vector_type(4)));
typedef unsigned long long u64;

// ---- workspace layout (in floats) ----
#define OFF_WE     0
#define OFF_CTX    512
#define OFF_H      (OFF_CTX + BB*HH)          // 66048
#define OFF_C      (OFF_H + BB*HH)            // 131584
#define OFF_GATES  (OFF_C + BB*HH)            // 197120
#define OFF_SLOTS  (OFF_GATES + BB*2048)      // 459264
#define OFF_GCTX   (OFF_SLOTS + 2*NT*BB)      // 466176
#define OFF_GIN    (OFF_GCTX + BB*2048)       // 728320
#define WS_FULL_FLOATS (OFF_GIN + NT*BB*2048) // 7,806,208 floats
// ---- per-step MFMA layout (fallback, round-2 verified) ----
#define OFF_WHI    WS_FULL_FLOATS                    // ushort[VV*512]
#define OFF_WLO    (OFF_WHI + VV*256)
#define OFF_HHI    (OFF_WLO + VV*256)                // ushort[BB*512]
#define OFF_HLO    (OFF_HHI + BB*256)
#define OFF_PART   (OFF_HLO + BB*256)                // u64[NT][NBLK][BB]
#define WS_MFMA_FLOATS (OFF_PART + NT*NBLK*BB*2)     // ~106 MB
// ---- batched MFMA layout (primary) ----
#define OFF_WHI_B   WS_FULL_FLOATS                   // ushort[VV*512]
#define OFF_WLO_B   (OFF_WHI_B + VV*256)
#define OFF_HALLHI  (OFF_WLO_B + VV*256)             // ushort[NT*BB*512]
#define OFF_HALLLO  (OFF_HALLHI + NT*BB*256)
#define OFF_PART_B  (OFF_HALLLO + NT*BB*256)         // u64[NT][NBLK][BB]
#define WS_BATCH_FLOATS (OFF_PART_B + NT*NBLK*BB*2)  // 28,177,408 floats = ~112.7 MB

__device__ __forceinline__ unsigned long long pack_max(float v, int n) {
    unsigned u = __float_as_uint(v);
    unsigned key = (u & 0x80000000u) ? ~u : (u | 0x80000000u);
    return ((unsigned long long)key << 32) | (unsigned)(~(unsigned)n);
}

__device__ __forceinline__ unsigned short bf16_rne(float x) {
    unsigned u = __float_as_uint(x);
    unsigned r = (u + 0x7fffu + ((u >> 16) & 1u)) >> 16;
    return (unsigned short)r;
}
__device__ __forceinline__ float bf16f(unsigned short h) {
    return __uint_as_float((unsigned)h << 16);
}
__device__ __forceinline__ u64 shfl_xor_u64(u64 v, int m) {
    unsigned lo = (unsigned)v, hi = (unsigned)(v >> 32);
    lo = __shfl_xor(lo, m, 64);
    hi = __shfl_xor(hi, m, 64);
    return ((u64)hi << 32) | lo;
}

// ---------------- init: h = elhs, c = 0, slots = 0 ----------------
__global__ void k_init(const float* __restrict__ elhs, float* __restrict__ h,
                       float* __restrict__ c, unsigned long long* __restrict__ slots) {
    int i = blockIdx.x * blockDim.x + threadIdx.x;
    if (i < BB * HH) { h[i] = elhs[i]; c[i] = 0.f; }
    if (i < NT * BB) slots[i] = 0ull;
}

// ---------------- vout[k] = sum_j vin[j] * W[j*ld + k], k in [0,512) ----------------
// Coalesced replacement for the old single-block k_we chain: 8 blocks x 64 cols,
// threads sweep contiguous 256B row segments; 4 j-groups LDS-reduced.
__global__ __launch_bounds__(256) void k_matvecT(const float* __restrict__ W, int ld,
                                                 const float* __restrict__ vin,
                                                 float* __restrict__ vout) {
    __shared__ float vs[HH];
    __shared__ float red[4][64];
    int tid = threadIdx.x;
    for (int j = tid; j < HH; j += 256) vs[j] = vin[j];
    __syncthreads();
    int c  = tid & 63;
    int jg = tid >> 6;
    int k  = blockIdx.x * 64 + c;
    float s = 0.f;
    #pragma unroll 4
    for (int j = jg * 128; j < jg * 128 + 128; ++j)
        s += vs[j] * W[(size_t)j * ld + k];
    red[jg][c] = s;
    __syncthreads();
    if (tid < 64)
        vout[blockIdx.x * 64 + tid] = red[0][tid] + red[1][tid] + red[2][tid] + red[3][tid];
}

// ---------------- attention (step-invariant) ----------------
__global__ __launch_bounds__(256) void k_attn(const float* __restrict__ eo, const float* __restrict__ we,
                                              float* __restrict__ ctx) {
    __shared__ float wsm[HH];
    __shared__ float sc[SS];
    int b = blockIdx.x, tid = threadIdx.x;
    for (int k = tid; k < HH; k += 256) wsm[k] = we[k];
    __syncthreads();
    int wid = tid >> 6, lane = tid & 63;
    const float* eob = eo + (size_t)b * SS * HH;
    for (int s = wid; s < SS; s += 4) {
        float p = 0.f;
        for (int k = lane; k < HH; k += 64) p += eob[s * HH + k] * wsm[k];
        for (int off = 32; off > 0; off >>= 1) p += __shfl_down(p, off, 64);
        if (lane == 0) sc[s] = p;
    }
    __syncthreads();
    if (wid == 0) {
        float a = (lane < SS) ? sc[lane] : -INFINITY;
        float bv = (lane + 64 < SS) ? sc[lane + 64] : -INFINITY;
        float m = fmaxf(a, bv);
        for (int off = 32; off > 0; off >>= 1) m = fmaxf(m, __shfl_down(m, off, 64));
        m = __shfl(m, 0, 64);
        float e0 = (lane < SS) ? expf(a - m) : 0.f;
        float e1 = (lane + 64 < SS) ? expf(bv - m) : 0.f;
        float ssum = e0 + e1;
        for (int off = 32; off > 0; off >>= 1) ssum += __shfl_down(ssum, off, 64);
        ssum = __shfl(ssum, 0, 64);
        float inv = 1.f / ssum;
        if (lane < SS) sc[lane] = e0 * inv;
        if (lane + 64 < SS) sc[lane + 64] = e1 * inv;
    }
    __syncthreads();
    for (int hh = tid; hh < HH; hh += 256) {
        float acc = 0.f;
        for (int s = 0; s < SS; ++s) acc += sc[s] * eob[s * HH + hh];
        ctx[b * HH + hh] = acc;
    }
}

// ---------------- G_in = X @ W_ih[:, :512]^T ----------------
__global__ __launch_bounds__(256) void k_gin(const float* __restrict__ emb, const int* __restrict__ targets,
                                             const float* __restrict__ Wih, float* __restrict__ gin) {
    const int n0 = blockIdx.x * 64, m0 = blockIdx.y * 64;
    __shared__ __align__(16) float As[32][68];
    __shared__ __align__(16) float Bs[32][68];
    int tid = threadIdx.x;
    int tx = tid & 15, ty = tid >> 4;
    float acc[4][4] = {};
    for (int kt = 0; kt < 512; kt += 32) {
        #pragma unroll
        for (int i = 0; i < 2; ++i) {
            int idx = tid + i * 256;
            int mm = idx >> 3, k4 = (idx & 7) * 4;
            int m = m0 + mm;
            int t = m >> 7, b = m & 127;
            int row = targets[b * 28 + t];
            float4 v = *(const float4*)(emb + (size_t)row * 512 + kt + k4);
            As[k4 + 0][mm] = v.x; As[k4 + 1][mm] = v.y; As[k4 + 2][mm] = v.z; As[k4 + 3][mm] = v.w;
        }
        #pragma unroll
        for (int i = 0; i < 2; ++i) {
            int idx = tid + i * 256;
            int nn = idx >> 3, k4 = (idx & 7) * 4;
            float4 v = *(const float4*)(Wih + (size_t)(n0 + nn) * 1024 + kt + k4);
            Bs[k4 + 0][nn] = v.x; Bs[k4 + 1][nn] = v.y; Bs[k4 + 2][nn] = v.z; Bs[k4 + 3][nn] = v.w;
        }
        __syncthreads();
        #pragma unroll
        for (int k = 0; k < 32; ++k) {
            float4 a = *(const float4*)&As[k][ty * 4];
            float4 b4 = *(const float4*)&Bs[k][tx * 4];
            float av[4] = {a.x, a.y, a.z, a.w}, bv[4] = {b4.x, b4.y, b4.z, b4.w};
            #pragma unroll
            for (int i = 0; i < 4; ++i)
                #pragma unroll
                for (int j = 0; j < 4; ++j) acc[i][j] += av[i] * bv[j];
        }
        __syncthreads();
    }
    #pragma unroll
    for (int i = 0; i < 4; ++i) {
        int m = m0 + ty * 4 + i;
        float4 o = {acc[i][0], acc[i][1], acc[i][2], acc[i][3]};
        *(float4*)(gin + (size_t)m * 2048 + n0 + tx * 4) = o;
    }
}

// ---------------- gctx = ctx @ W_ih[:, 512:]^T + b_ih + b_hh ----------------
__global__ __launch_bounds__(256) void k_gctx(const float* __restrict__ ctx, const float* __restrict__ Wih,
                                              const float* __restrict__ bih, const float* __restrict__ bhh,
                                              float* __restrict__ gctx) {
    const int n0 = blockIdx.x * 64, m0 = blockIdx.y * 32;
    __shared__ __align__(16) float As[32][36];
    __shared__ __align__(16) float Bs[32][68];
    int tid = threadIdx.x;
    int tx = tid & 15, ty = tid >> 4;
    float acc[2][4] = {};
    for (int kt = 0; kt < 512; kt += 32) {
        {
            int mm = tid >> 3, k4 = (tid & 7) * 4;
            float4 v = *(const float4*)(ctx + (size_t)(m0 + mm) * 512 + kt + k4);
            As[k4 + 0][mm] = v.x; As[k4 + 1][mm] = v.y; As[k4 + 2][mm] = v.z; As[k4 + 3][mm] = v.w;
        }
        #pragma unroll
        for (int i = 0; i < 2; ++i) {
            int idx = tid + i * 256;
            int nn = idx >> 3, k4 = (idx & 7) * 4;
            float4 v = *(const float4*)(Wih + (size_t)(n0 + nn) * 1024 + 512 + kt + k4);
            Bs[k4 + 0][nn] = v.x; Bs[k4 + 1][nn] = v.y; Bs[k4 + 2][nn] = v.z; Bs[k4 + 3][nn] = v.w;
        }
        __syncthreads();
        #pragma unroll
        for (int k = 0; k < 32; ++k) {
            float a0 = As[k][ty * 2], a1 = As[k][ty * 2 + 1];
            float4 b4 = *(const float4*)&Bs[k][tx * 4];
            float bv[4] = {b4.x, b4.y, b4.z, b4.w};
            #pragma unroll
            for (int j = 0; j < 4; ++j) { acc[0][j] += a0 * bv[j]; acc[1][j] += a1 * bv[j]; }
        }
        __syncthreads();
    }
    #pragma unroll
    for (int i = 0; i < 2; ++i) {
        int b = m0 + ty * 2 + i;
        int n = n0 + tx * 4;
        float4 o = {acc[i][0] + bih[n] + bhh[n], acc[i][1] + bih[n + 1] + bhh[n + 1],
                    acc[i][2] + bih[n + 2] + bhh[n + 2], acc[i][3] + bih[n + 3] + bhh[n + 3]};
        *(float4*)(gctx + (size_t)b * 2048 + n) = o;
    }
}

// ---------------- gates GEMM ----------------
template <bool FULL>
__global__ __launch_bounds__(256) void k_gates(const float* __restrict__ emb, const int* __restrict__ targets,
                                               const float* __restrict__ ctx, const float* __restrict__ h,
                                               const float* __restrict__ Wih, const float* __restrict__ Whh,
                                               const float* __restrict__ bih, const float* __restrict__ bhh,
                                               const float* __restrict__ gin, const float* __restrict__ gctx,
                                               float* __restrict__ gates, int t) {
    const int n0 = blockIdx.x * 64, m0 = blockIdx.y * 32;
    __shared__ __align__(16) float As[32][36];
    __shared__ __align__(16) float Bs[32][68];
    int tid = threadIdx.x;
    int tx = tid & 15, ty = tid >> 4;
    float acc[2][4] = {};
    const int KTOT = FULL ? 1536 : 512;
    for (int kt = 0; kt < KTOT; kt += 32) {
        {
            int mm = tid >> 3, k4 = (tid & 7) * 4;
            int b = m0 + mm, k = kt + k4;
            const float* src;
            if (FULL) {
                if (k < 512) { int row = targets[b * 28 + t]; src = emb + (size_t)row * 512 + k; }
                else if (k < 1024) src = ctx + (size_t)b * 512 + (k - 512);
                else src = h + (size_t)b * 512 + (k - 1024);
            } else {
                src = h + (size_t)b * 512 + k;
            }
            float4 v = *(const float4*)src;
            As[k4 + 0][mm] = v.x; As[k4 + 1][mm] = v.y; As[k4 + 2][mm] = v.z; As[k4 + 3][mm] = v.w;
        }
        #pragma unroll
        for (int i = 0; i < 2; ++i) {
            int idx = tid + i * 256;
            int nn = idx >> 3, k4 = (idx & 7) * 4;
            int n = n0 + nn, k = kt + k4;
            const float* src;
            if (FULL) {
                if (k < 1024) src = Wih + (size_t)n * 1024 + k;
                else src = Whh + (size_t)n * 512 + (k - 1024);
            } else {
                src = Whh + (size_t)n * 512 + k;
            }
            float4 v = *(const float4*)src;
            Bs[k4 + 0][nn] = v.x; Bs[k4 + 1][nn] = v.y; Bs[k4 + 2][nn] = v.z; Bs[k4 + 3][nn] = v.w;
        }
        __syncthreads();
        #pragma unroll
        for (int k = 0; k < 32; ++k) {
            float a0 = As[k][ty * 2], a1 = As[k][ty * 2 + 1];
            float4 b4 = *(const float4*)&Bs[k][tx * 4];
            float bv[4] = {b4.x, b4.y, b4.z, b4.w};
            #pragma unroll
            for (int j = 0; j < 4; ++j) { acc[0][j] += a0 * bv[j]; acc[1][j] += a1 * bv[j]; }
        }
        __syncthreads();
    }
    #pragma unroll
    for (int i = 0; i < 2; ++i) {
        int b = m0 + ty * 2 + i;
        int n = n0 + tx * 4;
        float base[4];
        if (FULL) {
            #pragma unroll
            for (int j = 0; j < 4; ++j) base[j] = bih[n + j] + bhh[n + j];
        } else {
            const float* g1 = gin + ((size_t)t * BB + b) * 2048 + n;
            const float* g2 = gctx + (size_t)b * 2048 + n;
            #pragma unroll
            for (int j = 0; j < 4; ++j) base[j] = g1[j] + g2[j];
        }
        float4 o = {acc[i][0] + base[0], acc[i][1] + base[1], acc[i][2] + base[2], acc[i][3] + base[3]};
        *(float4*)(gates + (size_t)b * 2048 + n) = o;
    }
}

// ---------------- LSTM pointwise (fp32-only path) ----------------
__global__ void k_lstm(const float* __restrict__ gates, float* __restrict__ h, float* __restrict__ c) {
    int idx = blockIdx.x * blockDim.x + threadIdx.x;
    int b = idx >> 9, j = idx & 511;
    const float* g = gates + (size_t)b * 2048;
    float iv = g[j], fv = g[512 + j], gv = g[1024 + j], ov = g[1536 + j];
    float si = 1.f / (1.f + expf(-iv));
    float sf = 1.f / (1.f + expf(-fv));
    float so = 1.f / (1.f + expf(-ov));
    float c2 = sf * c[idx] + si * tanhf(gv);
    c[idx] = c2;
    h[idx] = so * tanhf(c2);
}

// ---------------- LSTM pointwise + bf16 hi/lo split of h (MFMA paths) ----------------
__global__ void k_lstm2(const float* __restrict__ gates, float* __restrict__ h, float* __restrict__ c,
                        unsigned short* __restrict__ hHi, unsigned short* __restrict__ hLo) {
    int idx = blockIdx.x * blockDim.x + threadIdx.x;
    int b = idx >> 9, j = idx & 511;
    const float* g = gates + (size_t)b * 2048;
    float iv = g[j], fv = g[512 + j], gv = g[1024 + j], ov = g[1536 + j];
    float si = 1.f / (1.f + expf(-iv));
    float sf = 1.f / (1.f + expf(-fv));
    float so = 1.f / (1.f + expf(-ov));
    float c2 = sf * c[idx] + si * tanhf(gv);
    c[idx] = c2;
    float hv = so * tanhf(c2);
    h[idx] = hv;
    unsigned short hh = bf16_rne(hv);
    hHi[idx] = hh;
    hLo[idx] = bf16_rne(hv - bf16f(hh));
}

// ---------------- one-time split: fp32 -> (bf16 hi, bf16 lo) ----------------
__global__ __launch_bounds__(256) void k_split(const float* __restrict__ src, unsigned short* __restrict__ hi,
                                               unsigned short* __restrict__ lo, int n4) {
    int i = blockIdx.x * 256 + threadIdx.x;
    if (i >= n4) return;
    float4 v = ((const float4*)src)[i];
    unsigned short h0 = bf16_rne(v.x), h1 = bf16_rne(v.y), h2 = bf16_rne(v.z), h3 = bf16_rne(v.w);
    ushort4 hv = {h0, h1, h2, h3};
    ushort4 lv = {bf16_rne(v.x - bf16f(h0)), bf16_rne(v.y - bf16f(h1)),
                  bf16_rne(v.z - bf16f(h2)), bf16_rne(v.w - bf16f(h3))};
    ((ushort4*)hi)[i] = hv;
    ((ushort4*)lo)[i] = lv;
}

// ---------------- BATCHED vocab projection: all 27 steps in one dispatch ----------------
// M = NT*128 = 3456, N = 30000, K = 512, split-bf16 3-product MFMA.
// XCD-aware slab-major swizzle: dispatch round-robins bids over the 8 XCDs
// (XCD = bid&7), so XCD x executes r = bid>>3 in order. We map r = g*27 + t,
// nblk = g*8 + x: each XCD runs one weight slab's 27 t-blocks back-to-back,
// so the 128KB slab is fetched once per XCD-visit and L2-hit 26 times
// (round-3 counters showed FETCH = 27 x full weights = zero cross-block reuse
// with the naive bid/NT mapping). Grid padded to 8*59*27; early-exit nblk>=469.
// Single-buffered fragment loads (round-2: double-buffer spilled); 5 blocks/CU
// (VGPR=76 measured, cap 102) for TLP latency hiding.
__global__ __launch_bounds__(256, 5) void k_vprojB(
    const unsigned short* __restrict__ hAllHi, const unsigned short* __restrict__ hAllLo,
    const unsigned short* __restrict__ wHi, const unsigned short* __restrict__ wLo,
    const float* __restrict__ bout, float* __restrict__ out,
    u64* __restrict__ part)
{
    const int bid = blockIdx.x;
    const int x = bid & 7;
    const int r = bid >> 3;
    const int g2 = r / NT;
    const int t = r - g2 * NT;
    const int nblk = g2 * 8 + x;
    if (nblk >= NBLK) return;
    const int n0 = nblk * 64;
    const int tid = threadIdx.x;
    const int lane = tid & 63;
    const int wv = tid >> 6;
    const int g = lane >> 4;
    const int q = lane & 15;

    int aIdx[2];
    int bIdx[4], colv[4];
    float bo[4];
    #pragma unroll
    for (int mt = 0; mt < 2; ++mt)
        aIdx[mt] = ((t * BB) + wv * 32 + mt * 16 + q) * 512 + g * 8;
    #pragma unroll
    for (int nt = 0; nt < 4; ++nt) {
        int col = n0 + nt * 16 + q;
        colv[nt] = col;
        int cc = col < VV ? col : (VV - 1);   // clamped dup can't win argmax (larger idx loses tie)
        bIdx[nt] = cc * 512 + g * 8;
        bo[nt] = bout[cc];
    }

    f32x4 zero = {0.f, 0.f, 0.f, 0.f};
    f32x4 acc[2][4];
    #pragma unroll
    for (int mt = 0; mt < 2; ++mt)
        #pragma unroll
        for (int nt = 0; nt < 4; ++nt) acc[mt][nt] = zero;

    for (int s = 0; s < 16; ++s) {
        const int K = s * 32;
        bf16x8 aH[2], aL[2], bH[4], bL[4];
        #pragma unroll
        for (int mt = 0; mt < 2; ++mt) {
            aH[mt] = *(const bf16x8*)(hAllHi + aIdx[mt] + K);
            aL[mt] = *(const bf16x8*)(hAllLo + aIdx[mt] + K);
        }
        #pragma unroll
        for (int nt = 0; nt < 4; ++nt) {
            bH[nt] = *(const bf16x8*)(wHi + bIdx[nt] + K);
            bL[nt] = *(const bf16x8*)(wLo + bIdx[nt] + K);
        }
        #pragma unroll
        for (int mt = 0; mt < 2; ++mt)
            #pragma unroll
            for (int nt = 0; nt < 4; ++nt) {
                acc[mt][nt] = __builtin_amdgcn_mfma_f32_16x16x32_bf16(aH[mt], bH[nt], acc[mt][nt], 0, 0, 0);
                acc[mt][nt] = __builtin_amdgcn_mfma_f32_16x16x32_bf16(aH[mt], bL[nt], acc[mt][nt], 0, 0, 0);
                acc[mt][nt] = __builtin_amdgcn_mfma_f32_16x16x32_bf16(aL[mt], bH[nt], acc[mt][nt], 0, 0, 0);
            }
    }

    // epilogue: bias, store logits, per-row argmax partial (C/D: col=lane&15, row=4*(lane>>4)+reg)
    #pragma unroll
    for (int mt = 0; mt < 2; ++mt) {
        #pragma unroll
        for (int rr = 0; rr < 4; ++rr) {
            int row = wv * 32 + mt * 16 + 4 * g + rr;   // batch index 0..127
            u64 pk = 0ull;
            #pragma unroll
            for (int nt = 0; nt < 4; ++nt) {
                float v = acc[mt][nt][rr] + bo[nt];
                int col = colv[nt];
                if (col < VV) out[((size_t)row * NT + t) * VV + col] = v;
                u64 p2 = pack_max(v, col);
                if (p2 > pk) pk = p2;
            }
            #pragma unroll
            for (int m_ = 1; m_ < 16; m_ <<= 1) {
                u64 o = shfl_xor_u64(pk, m_);
                if (o > pk) pk = o;
            }
            if (q == 0) part[((size_t)t * NBLK + nblk) * BB + row] = pk;
        }
    }
}

// ---------------- per-step MFMA vproj (fallback, round-2 verified) ----------------
__global__ __launch_bounds__(256, 2) void k_vproj2(
    const unsigned short* __restrict__ hHi, const unsigned short* __restrict__ hLo,
    const unsigned short* __restrict__ wHi, const unsigned short* __restrict__ wLo,
    const float* __restrict__ bout, float* __restrict__ out,
    u64* __restrict__ part, int t)
{
    const int tid = threadIdx.x;
    const int lane = tid & 63;
    const int wv = tid >> 6;
    const int wm = wv >> 1;
    const int wn = wv & 1;
    const int g = lane >> 4;
    const int q = lane & 15;
    const int n0 = blockIdx.x * 64;

    int aIdx[4];
    int bIdx[2], colv[2];
    float bo[2];
    #pragma unroll
    for (int mt = 0; mt < 4; ++mt) aIdx[mt] = (wm * 64 + mt * 16 + q) * 512 + g * 8;
    #pragma unroll
    for (int nt = 0; nt < 2; ++nt) {
        int col = n0 + wn * 32 + nt * 16 + q;
        colv[nt] = col;
        int cc = col < VV ? col : (VV - 1);
        bIdx[nt] = cc * 512 + g * 8;
        bo[nt] = bout[cc];
    }

    f32x4 zero = {0.f, 0.f, 0.f, 0.f};
    f32x4 acc[4][2];
    #pragma unroll
    for (int mt = 0; mt < 4; ++mt)
        #pragma unroll
        for (int nt = 0; nt < 2; ++nt) acc[mt][nt] = zero;

    for (int s = 0; s < 16; ++s) {
        const int K = s * 32;
        bf16x8 aH[4], aL[4], bH[2], bL[2];
        #pragma unroll
        for (int mt = 0; mt < 4; ++mt) {
            aH[mt] = *(const bf16x8*)(hHi + aIdx[mt] + K);
            aL[mt] = *(const bf16x8*)(hLo + aIdx[mt] + K);
        }
        #pragma unroll
        for (int nt = 0; nt < 2; ++nt) {
            bH[nt] = *(const bf16x8*)(wHi + bIdx[nt] + K);
            bL[nt] = *(const bf16x8*)(wLo + bIdx[nt] + K);
        }
        #pragma unroll
        for (int mt = 0; mt < 4; ++mt)
            #pragma unroll
            for (int nt = 0; nt < 2; ++nt) {
                acc[mt][nt] = __builtin_amdgcn_mfma_f32_16x16x32_bf16(aH[mt], bH[nt], acc[mt][nt], 0, 0, 0);
                acc[mt][nt] = __builtin_amdgcn_mfma_f32_16x16x32_bf16(aH[mt], bL[nt], acc[mt][nt], 0, 0, 0);
                acc[mt][nt] = __builtin_amdgcn_mfma_f32_16x16x32_bf16(aL[mt], bH[nt], acc[mt][nt], 0, 0, 0);
            }
    }

    __shared__ u64 red[BB][2];
    #pragma unroll
    for (int mt = 0; mt < 4; ++mt) {
        #pragma unroll
        for (int rr = 0; rr < 4; ++rr) {
            int row = wm * 64 + mt * 16 + 4 * g + rr;
            u64 pk = 0ull;
            #pragma unroll
            for (int nt = 0; nt < 2; ++nt) {
                float v = acc[mt][nt][rr] + bo[nt];
                int col = colv[nt];
                if (col < VV) out[((size_t)row * NT + t) * VV + col] = v;
                u64 p2 = pack_max(v, col);
                if (p2 > pk) pk = p2;
            }
            #pragma unroll
            for (int m_ = 1; m_ < 16; m_ <<= 1) {
                u64 o = shfl_xor_u64(pk, m_);
                if (o > pk) pk = o;
            }
            if (q == 0) red[row][wn] = pk;
        }
    }
    __syncthreads();
    if (tid < BB) {
        u64 a = red[tid][0], b2 = red[tid][1];
        part[((size_t)t * NBLK + blockIdx.x) * BB + tid] = a > b2 ? a : b2;
    }
}

// ---------------- old fp32 vproj (deep fallback) ----------------
__global__ __launch_bounds__(256) void k_vproj(const float* __restrict__ h, const float* __restrict__ Wout,
                                               const float* __restrict__ bout, float* __restrict__ out,
                                               unsigned long long* __restrict__ slots, int t) {
    const int n0 = blockIdx.x * 64, m0 = blockIdx.y * 64;
    __shared__ __align__(16) float As[32][68];
    __shared__ __align__(16) float Bs[32][68];
    __shared__ unsigned long long red[64][17];
    int tid = threadIdx.x;
    int tx = tid & 15, ty = tid >> 4;
    float acc[4][4] = {};
    for (int kt = 0; kt < 512; kt += 32) {
        #pragma unroll
        for (int i = 0; i < 2; ++i) {
            int idx = tid + i * 256;
            int mm = idx >> 3, k4 = (idx & 7) * 4;
            float4 v = *(const float4*)(h + (size_t)(m0 + mm) * 512 + kt + k4);
            As[k4 + 0][mm] = v.x; As[k4 + 1][mm] = v.y; As[k4 + 2][mm] = v.z; As[k4 + 3][mm] = v.w;
        }
        #pragma unroll
        for (int i = 0; i < 2; ++i) {
            int idx = tid + i * 256;
            int nn = idx >> 3, k4 = (idx & 7) * 4;
            int n = n0 + nn; if (n >= VV) n = VV - 1;
            float4 v = *(const float4*)(Wout + (size_t)n * 512 + kt + k4);
            Bs[k4 + 0][nn] = v.x; Bs[k4 + 1][nn] = v.y; Bs[k4 + 2][nn] = v.z; Bs[k4 + 3][nn] = v.w;
        }
        __syncthreads();
        #pragma unroll
        for (int k = 0; k < 32; ++k) {
            float4 a = *(const float4*)&As[k][ty * 4];
            float4 b4 = *(const float4*)&Bs[k][tx * 4];
            float av[4] = {a.x, a.y, a.z, a.w}, bv[4] = {b4.x, b4.y, b4.z, b4.w};
            #pragma unroll
            for (int i = 0; i < 4; ++i)
                #pragma unroll
                for (int j = 0; j < 4; ++j) acc[i][j] += av[i] * bv[j];
        }
        __syncthreads();
    }
    #pragma unroll
    for (int i = 0; i < 4; ++i) {
        int m = m0 + ty * 4 + i;
        int n = n0 + tx * 4;
        float vals[4];
        #pragma unroll
        for (int j = 0; j < 4; ++j) vals[j] = acc[i][j] + ((n + j < VV) ? bout[n + j] : 0.f);
        size_t ob = ((size_t)m * NT + t) * VV;
        if (n + 3 < VV) {
            float4 o = {vals[0], vals[1], vals[2], vals[3]};
            *(float4*)(out + ob + n) = o;
        } else {
            for (int j = 0; j < 4; ++j) if (n + j < VV) out[ob + n + j] = vals[j];
        }
        unsigned long long p = 0ull;
        #pragma unroll
        for (int j = 0; j < 4; ++j)
            if (n + j < VV) {
                unsigned long long pk = pack_max(vals[j], n + j);
                if (pk > p) p = pk;
            }
        red[ty * 4 + i][tx] = p;
    }
    __syncthreads();
    if (tid < 64) {
        unsigned long long best = red[tid][0];
        #pragma unroll
        for (int j = 1; j < 16; ++j) { unsigned long long q = red[tid][j]; if (q > best) best = q; }
        atomicMax(&slots[t * BB + (m0 + tid)], best);
    }
}

// ---------------- decode predictions (fp32 path) ----------------
__global__ void k_final(const unsigned long long* __restrict__ slots, float* __restrict__ out) {
    int i = blockIdx.x * blockDim.x + threadIdx.x;
    if (i >= NT * BB) return;
    int t = i / BB, b = i % BB;
    unsigned idx = ~(unsigned)(slots[i] & 0xffffffffull);
    out[(size_t)BB * NT * VV + (size_t)b * NT + t] = (float)idx;
}

// ---------------- decode predictions from per-block partials (MFMA paths) ----------------
__global__ void k_final2(const u64* __restrict__ part, float* __restrict__ out) {
    int i = blockIdx.x * blockDim.x + threadIdx.x;   // t*128 + b
    if (i >= NT * BB) return;
    int t = i >> 7, b = i & 127;
    const u64* p = part + (size_t)t * NBLK * BB + b;
    u64 best = 0ull;
    for (int nb = 0; nb < NBLK; ++nb) {
        u64 v = p[(size_t)nb * BB];
        if (v > best) best = v;
    }
    unsigned idx = ~(unsigned)(best & 0xffffffffull);
    out[(size_t)BB * NT * VV + (size_t)b * NT + t] = (float)idx;
}

extern "C" void kernel_launch(void* const* d_in, const int* in_sizes, int n_in,
                              void* d_out, int out_size, void* d_ws, size_t ws_size,
                              hipStream_t stream) {
    const float* elhs    = (const float*)d_in[0];
    const float* eo      = (const float*)d_in[1];
    const int*   targets = (const int*)d_in[2];
    const float* emb     = (const float*)d_in[3];
    const float* W1      = (const float*)d_in[4];
    const float* W2      = (const float*)d_in[6];
    const float* W3      = (const float*)d_in[8];
    const float* W4      = (const float*)d_in[10];
    const float* watt    = (const float*)d_in[12];
    const float* Wih     = (const float*)d_in[13];
    const float* Whh     = (const float*)d_in[14];
    const float* bih     = (const float*)d_in[15];
    const float* bhh     = (const float*)d_in[16];
    const float* Wout    = (const float*)d_in[17];
    const float* bout    = (const float*)d_in[18];

    float* out = (float*)d_out;
    float* ws  = (float*)d_ws;
    float* we    = ws + OFF_WE;
    float* ctx   = ws + OFF_CTX;
    float* h     = ws + OFF_H;
    float* c     = ws + OFF_C;
    float* gates = ws + OFF_GATES;
    unsigned long long* slots = (unsigned long long*)(ws + OFF_SLOTS);
    float* gctx  = ws + OFF_GCTX;
    float* gin   = ws + OFF_GIN;

    const bool use_gin   = ws_size >= (size_t)WS_FULL_FLOATS * sizeof(float);
    const bool use_batch = ws_size >= (size_t)WS_BATCH_FLOATS * sizeof(float);
    const bool use_mfma  = !use_batch && ws_size >= (size_t)WS_MFMA_FLOATS * sizeof(float);

    k_init<<<256, 256, 0, stream>>>(elhs, h, c, slots);
    // we-chain: v <- watt; v <- W4^T v; W3^T; W2^T; then first-512-cols of W1^T.
    // gates buffer is free until the t-loop — use it as ping-pong temp.
    {
        float* vtmp = gates;
        k_matvecT<<<8, 256, 0, stream>>>(W4, HH, watt, vtmp);
        k_matvecT<<<8, 256, 0, stream>>>(W3, HH, vtmp, we);
        k_matvecT<<<8, 256, 0, stream>>>(W2, HH, we, vtmp);
        k_matvecT<<<8, 256, 0, stream>>>(W1, 2 * HH, vtmp, we);
    }
    k_attn<<<BB, 256, 0, stream>>>(eo, we, ctx);
    if (use_gin) {
        k_gin<<<dim3(32, 54), 256, 0, stream>>>(emb, targets, Wih, gin);
        k_gctx<<<dim3(32, 4), 256, 0, stream>>>(ctx, Wih, bih, bhh, gctx);
    }

    if (use_batch) {
        unsigned short* wHi    = (unsigned short*)(ws + OFF_WHI_B);
        unsigned short* wLo    = (unsigned short*)(ws + OFF_WLO_B);
        unsigned short* hAllHi = (unsigned short*)(ws + OFF_HALLHI);
        unsigned short* hAllLo = (unsigned short*)(ws + OFF_HALLLO);
        u64* part = (u64*)(ws + OFF_PART_B);
        k_split<<<(VV * 128 + 255) / 256, 256, 0, stream>>>(Wout, wHi, wLo, VV * 128);
        for (int t = 0; t < NT; ++t) {
            if (use_gin)
                k_gates<false><<<dim3(32, 4), 256, 0, stream>>>(emb, targets, ctx, h, Wih, Whh, bih, bhh, gin, gctx, gates, t);
            else
                k_gates<true><<<dim3(32, 4), 256, 0, stream>>>(emb, targets, ctx, h, Wih, Whh, bih, bhh, gin, gctx, gates, t);
            k_lstm2<<<128, 512, 0, stream>>>(gates, h, c,
                                             hAllHi + (size_t)t * BB * 512,
                                             hAllLo + (size_t)t * BB * 512);
        }
        k_vprojB<<<8 * 59 * NT, 256, 0, stream>>>(hAllHi, hAllLo, wHi, wLo, bout, out, part);
        k_final2<<<14, 256, 0, stream>>>(part, out);
    } else if (use_mfma) {
        unsigned short* wHi = (unsigned short*)(ws + OFF_WHI);
        unsigned short* wLo = (unsigned short*)(ws + OFF_WLO);
        unsigned short* hHi = (unsigned short*)(ws + OFF_HHI);
        unsigned short* hLo = (unsigned short*)(ws + OFF_HLO);
        u64* part = (u64*)(ws + OFF_PART);
        k_split<<<(VV * 128 + 255) / 256, 256, 0, stream>>>(Wout, wHi, wLo, VV * 128);
        for (int t = 0; t < NT; ++t) {
            if (use_gin)
                k_gates<false><<<dim3(32, 4), 256, 0, stream>>>(emb, targets, ctx, h, Wih, Whh, bih, bhh, gin, gctx, gates, t);
            else
                k_gates<true><<<dim3(32, 4), 256, 0, stream>>>(emb, targets, ctx, h, Wih, Whh, bih, bhh, gin, gctx, gates, t);
            k_lstm2<<<128, 512, 0, stream>>>(gates, h, c, hHi, hLo);
            k_vproj2<<<NBLK, 256, 0, stream>>>(hHi, hLo, wHi, wLo, bout, out, part, t);
        }
        k_final2<<<14, 256, 0, stream>>>(part, out);
    } else {
        for (int t = 0; t < NT; ++t) {
            if (use_gin)
                k_gates<false><<<dim3(32, 4), 256, 0, stream>>>(emb, targets, ctx, h, Wih, Whh, bih, bhh, gin, gctx, gates, t);
            else
                k_gates<true><<<dim3(32, 4), 256, 0, stream>>>(emb, targets, ctx, h, Wih, Whh, bih, bhh, gin, gctx, gates, t);
            k_lstm<<<128, 512, 0, stream>>>(gates, h, c);
            k_vproj<<<dim3(469, 2), 256, 0, stream>>>(h, Wout, bout, out, slots, t);
        }
        k_final<<<14, 256, 0, stream>>>(slots, out);
    }
}